// Round 4
// baseline (439.637 us; speedup 1.0000x reference)
//
#include <hip/hip_runtime.h>
#include <hip/hip_bf16.h>
#include <math.h>

typedef __hip_bfloat16 bf16;
typedef __attribute__((ext_vector_type(8))) short s16x8;
typedef __attribute__((ext_vector_type(4))) float f32x4;

__device__ __forceinline__ float siluf(float x) { return x / (1.f + __expf(-x)); }
__device__ __forceinline__ float bits2f(unsigned short u) {
    union { float f; unsigned i; } v; v.i = ((unsigned)u) << 16; return v.f;
}
__device__ __forceinline__ unsigned short f2bits(float f) {
    return (unsigned short)__bfloat16_as_ushort(__float2bfloat16(f));
}

// ---------------- workspace offsets (float units) ----------------
#define KFL 1024
#define OFF_UB   (768*KFL)
#define OFF_X32  (1280*KFL)
#define OFF_X2B  (2304*KFL)
#define OFF_BMB  (2816*KFL)
#define OFF_CMB  (3840*KFL)
#define OFF_DTP  (4864*KFL)
#define OFF_ZG   (4928*KFL)
#define OFF_YGB  (5440*KFL)
#define OFF_YOUT (1280*KFL)
#define OFF_Z1   (2816*KFL)
#define OFF_ZNB  (3840*KFL)
#define OFF_QKV  (4352*KFL)
#define OFF_OB   (5888*KFL)
#define OFF_Z2   (6400*KFL)
#define OFF_ZFB  (768*KFL)
#define OFF_SGB  (7424*KFL)
#define OFF_GGB  (1280*KFL)

// weight element offsets (bf16 elements, from ws base)
#define W_X    0
#define W_B    65536
#define W_C    196608
#define W_Z    327680
#define W_O    393216
#define W_QKV  458752
#define W_AO   655360
#define W_G    720896
#define W_U    983040
#define W_D    1245184

// ------- fused weight prep: fp32 -> bf16, transpose to [N,K], MIMO-mix folded into Wb ----
__global__ __launch_bounds__(256) void prep_w(
    const float* __restrict__ Wx, const float* __restrict__ Wb,
    const float* __restrict__ Wc, const float* __restrict__ Wz,
    const float* __restrict__ Wo, const float* __restrict__ Wqkv,
    const float* __restrict__ Wao, const float* __restrict__ Wg,
    const float* __restrict__ Wu, const float* __restrict__ Wd,
    const float* __restrict__ U, const float* __restrict__ V,
    unsigned short* __restrict__ out)
{
    int b = blockIdx.x;
    if (b >= 256 && b < 768) {
        // Wb with cross-head mixing folded in: Bt[n,k] = sum_g Mm[h,g]*Wb[k, g*128+nn]
        int idx = (b - 256) * 256 + threadIdx.x;
        int n = idx >> 8, k = idx & 255;
        int h = n >> 7, nn = n & 127;
        float acc = 0.f;
        #pragma unroll
        for (int g = 0; g < 4; g++) {
            float mm = 0.f;
            #pragma unroll
            for (int j = 0; j < 4; j++) mm += U[h * 4 + j] * V[g * 4 + j];
            acc += mm * Wb[k * 512 + g * 128 + nn];
        }
        out[W_B + idx] = f2bits(acc);
        return;
    }
    const float* src; int dst, kshift, Nn, trans, segb;
    if      (b < 256)  { src=Wx;   dst=W_X;   kshift=8;  Nn=256;  trans=1; segb=0; }
    else if (b < 1280) { src=Wc;   dst=W_C;   kshift=8;  Nn=512;  trans=1; segb=768; }
    else if (b < 1536) { src=Wz;   dst=W_Z;   kshift=8;  Nn=256;  trans=1; segb=1280; }
    else if (b < 1792) { src=Wo;   dst=W_O;   kshift=8;  Nn=256;  trans=1; segb=1536; }
    else if (b < 2560) { src=Wqkv; dst=W_QKV; kshift=8;  Nn=256;  trans=0; segb=1792; }
    else if (b < 2816) { src=Wao;  dst=W_AO;  kshift=8;  Nn=256;  trans=0; segb=2560; }
    else if (b < 3840) { src=Wg;   dst=W_G;   kshift=8;  Nn=1024; trans=1; segb=2816; }
    else if (b < 4864) { src=Wu;   dst=W_U;   kshift=8;  Nn=1024; trans=1; segb=3840; }
    else               { src=Wd;   dst=W_D;   kshift=10; Nn=256;  trans=1; segb=4864; }
    int idx = (b - segb) * 256 + threadIdx.x;
    float v;
    if (trans) {
        int n = idx >> kshift, k = idx & ((1 << kshift) - 1);
        v = src[k * Nn + n];
    } else {
        v = src[idx];
    }
    out[dst + idx] = f2bits(v);
}

// ---------------- LN1: z (B,T,K,D) fp32 -> u bf16 band-major (BK,T,D) ----------------
__global__ __launch_bounds__(256) void ln1_kernel(const float* __restrict__ z,
    const float* __restrict__ g, const float* __restrict__ b,
    unsigned short* __restrict__ u)
{
    int r = blockIdx.x;
    int t = r & 255, bk = r >> 8;
    int b_ = bk >> 3, k = bk & 7;
    int src = ((b_ * 256 + t) * 8 + k) * 256;
    int d = threadIdx.x;
    float x = z[src + d];
    __shared__ float lds[4];
    float v = x;
    #pragma unroll
    for (int off = 32; off; off >>= 1) v += __shfl_xor(v, off, 64);
    if ((threadIdx.x & 63) == 0) lds[threadIdx.x >> 6] = v;
    __syncthreads();
    float mean = (lds[0] + lds[1] + lds[2] + lds[3]) * (1.f / 256.f);
    __syncthreads();
    float c = x - mean;
    v = c * c;
    #pragma unroll
    for (int off = 32; off; off >>= 1) v += __shfl_xor(v, off, 64);
    if ((threadIdx.x & 63) == 0) lds[threadIdx.x >> 6] = v;
    __syncthreads();
    float var = (lds[0] + lds[1] + lds[2] + lds[3]) * (1.f / 256.f);
    u[r * 256 + d] = f2bits(c * rsqrtf(var + 1e-5f) * g[d] + b[d]);
}

// generic f32-in LN -> bf16 out, identity row mapping
__global__ __launch_bounds__(256) void ln_f32_kernel(const float* __restrict__ zin,
    const float* __restrict__ g, const float* __restrict__ b,
    unsigned short* __restrict__ out)
{
    int r = blockIdx.x;
    int d = threadIdx.x;
    float x = zin[r * 256 + d];
    __shared__ float lds[4];
    float v = x;
    #pragma unroll
    for (int off = 32; off; off >>= 1) v += __shfl_xor(v, off, 64);
    if ((threadIdx.x & 63) == 0) lds[threadIdx.x >> 6] = v;
    __syncthreads();
    float mean = (lds[0] + lds[1] + lds[2] + lds[3]) * (1.f / 256.f);
    __syncthreads();
    float c = x - mean;
    v = c * c;
    #pragma unroll
    for (int off = 32; off; off >>= 1) v += __shfl_xor(v, off, 64);
    if ((threadIdx.x & 63) == 0) lds[threadIdx.x >> 6] = v;
    __syncthreads();
    float var = (lds[0] + lds[1] + lds[2] + lds[3]) * (1.f / 256.f);
    out[r * 256 + d] = f2bits(c * rsqrtf(var + 1e-5f) * g[d] + b[d]);
}

// ---- fused residual-add (with band-major transpose) + LN2: z1 fp32 + znb bf16 ----
__global__ __launch_bounds__(256) void addres_ln2_kernel(const float* __restrict__ z,
    const float* __restrict__ yout, const float* __restrict__ g,
    const float* __restrict__ b, float* __restrict__ z1,
    unsigned short* __restrict__ znb)
{
    int rt = blockIdx.x;                  // (b*256+t)*8+k
    int k = rt & 7, bt = rt >> 3;
    int t = bt & 255, b_ = bt >> 8;
    int rb = (b_ * 8 + k) * 256 + t;
    int d = threadIdx.x;
    float x = z[rt * 256 + d] + yout[rb * 256 + d];
    z1[rt * 256 + d] = x;
    __shared__ float lds[4];
    float v = x;
    #pragma unroll
    for (int off = 32; off; off >>= 1) v += __shfl_xor(v, off, 64);
    if ((threadIdx.x & 63) == 0) lds[threadIdx.x >> 6] = v;
    __syncthreads();
    float mean = (lds[0] + lds[1] + lds[2] + lds[3]) * (1.f / 256.f);
    __syncthreads();
    float c = x - mean;
    v = c * c;
    #pragma unroll
    for (int off = 32; off; off >>= 1) v += __shfl_xor(v, off, 64);
    if ((threadIdx.x & 63) == 0) lds[threadIdx.x >> 6] = v;
    __syncthreads();
    float var = (lds[0] + lds[1] + lds[2] + lds[3]) * (1.f / 256.f);
    znb[rt * 256 + d] = f2bits(c * rsqrtf(var + 1e-5f) * g[d] + b[d]);
}

// ---------------- MFMA bf16 GEMM: C[M,N]=A[M,K]@Bt[N,K]^T (+bias)(silu)(*mulin)(+resid)
__global__ __launch_bounds__(256) void mfma_gemm(
    const unsigned short* __restrict__ A, const unsigned short* __restrict__ Bt,
    const float* __restrict__ bias, const unsigned short* __restrict__ mulin,
    const float* __restrict__ resid, void* __restrict__ C,
    int N, int K, int act, int out_bf16)
{
    __shared__ unsigned short As[128 * 40];
    __shared__ unsigned short Bs[128 * 40];
    int tid = threadIdx.x;
    int n0 = blockIdx.x * 128, m0 = blockIdx.y * 128;
    int w = tid >> 6, l = tid & 63;
    int mwave = (w >> 1) * 64, nwave = (w & 1) * 64;
    f32x4 zero = {0.f, 0.f, 0.f, 0.f};
    f32x4 acc[4][4];
    #pragma unroll
    for (int i = 0; i < 4; i++)
        #pragma unroll
        for (int j = 0; j < 4; j++) acc[i][j] = zero;
    int srow = tid >> 2, sc = (tid & 3) * 8;
    const unsigned short* Ap = A + (m0 + srow) * K + sc;
    const unsigned short* Bp = Bt + (n0 + srow) * K + sc;
    int lq = l & 15, lh = l >> 4;
    int ko = lh * 8;
    for (int k0 = 0; k0 < K; k0 += 32) {
        uint4 a0 = *(const uint4*)(Ap + k0);
        uint4 a1 = *(const uint4*)(Ap + 64 * K + k0);
        uint4 b0 = *(const uint4*)(Bp + k0);
        uint4 b1 = *(const uint4*)(Bp + 64 * K + k0);
        if (k0) __syncthreads();
        *(uint4*)&As[srow * 40 + sc] = a0;
        *(uint4*)&As[(srow + 64) * 40 + sc] = a1;
        *(uint4*)&Bs[srow * 40 + sc] = b0;
        *(uint4*)&Bs[(srow + 64) * 40 + sc] = b1;
        __syncthreads();
        s16x8 bfr[4];
        #pragma unroll
        for (int nf = 0; nf < 4; nf++)
            bfr[nf] = *(const s16x8*)&Bs[(nwave + nf * 16 + lq) * 40 + ko];
        #pragma unroll
        for (int mf = 0; mf < 4; mf++) {
            s16x8 af = *(const s16x8*)&As[(mwave + mf * 16 + lq) * 40 + ko];
            #pragma unroll
            for (int nf = 0; nf < 4; nf++)
                acc[mf][nf] = __builtin_amdgcn_mfma_f32_16x16x32_bf16(af, bfr[nf], acc[mf][nf], 0, 0, 0);
        }
    }
    #pragma unroll
    for (int mf = 0; mf < 4; mf++) {
        #pragma unroll
        for (int nf = 0; nf < 4; nf++) {
            int n = n0 + nwave + nf * 16 + lq;
            float bs_ = bias ? bias[n] : 0.f;
            #pragma unroll
            for (int r = 0; r < 4; r++) {
                int m = m0 + mwave + mf * 16 + lh * 4 + r;
                float v = acc[mf][nf][r] + bs_;
                if (act) v = siluf(v);
                if (mulin) v *= bits2f(mulin[m * N + n]);
                if (resid) v += resid[m * N + n];
                if (out_bf16) ((unsigned short*)C)[m * N + n] = f2bits(v);
                else          ((float*)C)[m * N + n] = v;
            }
        }
    }
}

// ------- dt_raw = u_b @ Wdt (N=4) + softplus + decay/rotation, one wave/row -------
__global__ __launch_bounds__(64) void dt_small(const unsigned short* __restrict__ ub,
    const float* __restrict__ Wdt, const float* __restrict__ dt_bias,
    const float* __restrict__ A_log, const float* __restrict__ theta,
    float4* __restrict__ dtp)
{
    int r = blockIdx.x, l = threadIdx.x;
    ushort4 uv = *(const ushort4*)(ub + r * 256 + l * 4);
    float u0 = bits2f(uv.x), u1 = bits2f(uv.y), u2 = bits2f(uv.z), u3 = bits2f(uv.w);
    float4 w0 = *(const float4*)(Wdt + (l * 4 + 0) * 4);
    float4 w1 = *(const float4*)(Wdt + (l * 4 + 1) * 4);
    float4 w2 = *(const float4*)(Wdt + (l * 4 + 2) * 4);
    float4 w3 = *(const float4*)(Wdt + (l * 4 + 3) * 4);
    float p0 = u0 * w0.x + u1 * w1.x + u2 * w2.x + u3 * w3.x;
    float p1 = u0 * w0.y + u1 * w1.y + u2 * w2.y + u3 * w3.y;
    float p2 = u0 * w0.z + u1 * w1.z + u2 * w2.z + u3 * w3.z;
    float p3 = u0 * w0.w + u1 * w1.w + u2 * w2.w + u3 * w3.w;
    #pragma unroll
    for (int off = 32; off; off >>= 1) {
        p0 += __shfl_xor(p0, off, 64);
        p1 += __shfl_xor(p1, off, 64);
        p2 += __shfl_xor(p2, off, 64);
        p3 += __shfl_xor(p3, off, 64);
    }
    if (l == 0) {
        float pv[4] = {p0, p1, p2, p3};
        #pragma unroll
        for (int h = 0; h < 4; h++) {
            float xx = pv[h] + dt_bias[h];
            float d = (xx > 20.f) ? xx : log1pf(__expf(xx));
            float A = -__expf(A_log[h]);
            float mag = __expf(d * A);
            float ph = d * theta[h];
            dtp[r * 4 + h] = make_float4(d, mag * __cosf(ph), mag * __sinf(ph), 0.f);
        }
    }
}

// ---------------- causal depthwise conv (k=4) + silu, fp32 in -> bf16 out --------
__global__ __launch_bounds__(256) void conv_silu_kernel(const float* __restrict__ x,
    const float* __restrict__ w, unsigned short* __restrict__ out)
{
    int idx = blockIdx.x * 256 + threadIdx.x;
    int d = idx & 255;
    int r = idx >> 8;
    int t = r & 255;
    float acc = 0.f;
    #pragma unroll
    for (int kk = 0; kk < 4; kk++) {
        int tt = t + kk - 3;
        if (tt >= 0) acc += x[(r + kk - 3) * 256 + d] * w[d * 4 + kk];
    }
    out[idx] = f2bits(siluf(acc));
}

// ---------------- selective scan: wave-sync, p-split, XCD-swizzled, depth-8 ring ------
// 1024 blocks x 64 thr. scan = blk & 63 (keeps all 16 pg of a scan on one XCD under
// round-robin block->XCD), pg = blk >> 6. lane: p = pg*4 + (l>>4), n-set = (l&15)*8.
// Fused y*silu(u@Wz) gating -> writes bf16 ygb directly.
__global__ __launch_bounds__(64) void scan3_kernel(
    const unsigned short* __restrict__ xb, const unsigned short* __restrict__ Bb,
    const unsigned short* __restrict__ Cb, const float4* __restrict__ dtp,
    const float* __restrict__ Dsk, const unsigned short* __restrict__ zgb,
    unsigned short* __restrict__ ygb)
{
    int blk = blockIdx.x;
    int scan = blk & 63, pg = blk >> 6;
    int bk = scan >> 2, h = scan & 3;
    int l = threadIdx.x;
    int pp = l >> 4, q = l & 15;
    int p = pg * 4 + pp;
    int rbase = bk * 256;
    const unsigned short* bptr = Bb + (size_t)rbase * 512 + h * 128 + q * 8;
    const unsigned short* cptr = Cb + (size_t)rbase * 512 + h * 128 + q * 8;
    const unsigned short* xptr = xb + (size_t)rbase * 256 + h * 64 + p;
    const unsigned short* zptr = zgb + (size_t)rbase * 256 + h * 64 + p;
    const float4* dptr = dtp + rbase * 4 + h;
    float dsk = Dsk[h];
    float hre[8] = {0,0,0,0,0,0,0,0}, him[8] = {0,0,0,0,0,0,0,0};
    uint4 pbv[8], pcv[8];
    float4 ppk[8];
    float pxv[8], pzg[8];
    #pragma unroll
    for (int s = 0; s < 8; s++) {
        pbv[s] = *(const uint4*)(bptr + s * 512);
        pcv[s] = *(const uint4*)(cptr + s * 512);
        pxv[s] = bits2f(xptr[s * 256]);
        pzg[s] = bits2f(zptr[s * 256]);
        ppk[s] = dptr[s * 4];
    }
    #pragma unroll 8
    for (int t = 0; t < 256; t++) {
        int s = t & 7;
        uint4 bv = pbv[s], cv = pcv[s];
        float4 pk = ppk[s];
        float xv = pxv[s], zgv = pzg[s];
        int tn = t + 8; if (tn > 255) tn = 255;
        pbv[s] = *(const uint4*)(bptr + tn * 512);
        pcv[s] = *(const uint4*)(cptr + tn * 512);
        pxv[s] = bits2f(xptr[tn * 256]);
        pzg[s] = bits2f(zptr[tn * 256]);
        ppk[s] = dptr[tn * 4];
        float coef = pk.x * xv, arr = pk.y, aii = pk.z;
        const unsigned short* bu = (const unsigned short*)&bv;
        const unsigned short* cu = (const unsigned short*)&cv;
        float partial = 0.f;
        #pragma unroll
        for (int j = 0; j < 8; j++) {
            float bj = bits2f(bu[j]);
            float cj = bits2f(cu[j]);
            float hr = hre[j], hi = him[j];
            float nr = arr * hr - aii * hi + coef * bj;
            float ni = arr * hi + aii * hr;
            hre[j] = nr; him[j] = ni;
            partial += cj * nr;
        }
        partial += __shfl_xor(partial, 1, 64);
        partial += __shfl_xor(partial, 2, 64);
        partial += __shfl_xor(partial, 4, 64);
        partial += __shfl_xor(partial, 8, 64);
        if (q == 0)
            ygb[(size_t)(rbase + t) * 256 + h * 64 + p] =
                f2bits((partial + dsk * xv) * zgv);
    }
}

// ---------------- windowed attention (bf16 in/out) ----------------
__global__ __launch_bounds__(256) void attn_kernel(const unsigned short* __restrict__ qkv,
    unsigned short* __restrict__ o)
{
    int m = blockIdx.x >> 1, w = blockIdx.x & 1;
    int tid = threadIdx.x;
    int h = tid >> 6, d = tid & 63;
    __shared__ float qs[4][256], ks[4][256], vs[4][256];
    #pragma unroll
    for (int j = 0; j < 4; j++) {
        int row = m * 8 + w * 4 + j;
        int base = row * 768;
        qs[j][tid] = bits2f(qkv[base + tid]);
        ks[j][tid] = bits2f(qkv[base + 256 + tid]);
        vs[j][tid] = bits2f(qkv[base + 512 + tid]);
    }
    __syncthreads();
    float sc[4][4];
    #pragma unroll
    for (int qi = 0; qi < 4; qi++)
        #pragma unroll
        for (int ki = 0; ki < 4; ki++) {
            float v = qs[qi][h * 64 + d] * ks[ki][h * 64 + d];
            #pragma unroll
            for (int off = 32; off; off >>= 1) v += __shfl_xor(v, off, 64);
            sc[qi][ki] = v * 0.125f;
        }
    #pragma unroll
    for (int qi = 0; qi < 4; qi++) {
        float mx = fmaxf(fmaxf(sc[qi][0], sc[qi][1]), fmaxf(sc[qi][2], sc[qi][3]));
        float e0 = __expf(sc[qi][0] - mx), e1 = __expf(sc[qi][1] - mx);
        float e2 = __expf(sc[qi][2] - mx), e3 = __expf(sc[qi][3] - mx);
        float inv = 1.f / (e0 + e1 + e2 + e3);
        float ov = (e0 * vs[0][h * 64 + d] + e1 * vs[1][h * 64 + d] +
                    e2 * vs[2][h * 64 + d] + e3 * vs[3][h * 64 + d]) * inv;
        o[(m * 8 + w * 4 + qi) * 256 + h * 64 + d] = f2bits(ov);
    }
}

extern "C" void kernel_launch(void* const* d_in, const int* in_sizes, int n_in,
                              void* d_out, int out_size, void* d_ws, size_t ws_size,
                              hipStream_t stream)
{
    const float* z         = (const float*)d_in[0];
    const float* ln1_g     = (const float*)d_in[1];
    const float* ln1_b     = (const float*)d_in[2];
    const float* Wx        = (const float*)d_in[3];
    const float* conv_w    = (const float*)d_in[4];
    const float* Wz        = (const float*)d_in[5];
    const float* Wb        = (const float*)d_in[6];
    const float* Wc        = (const float*)d_in[7];
    const float* Wdt       = (const float*)d_in[8];
    const float* dt_bias   = (const float*)d_in[9];
    const float* A_log     = (const float*)d_in[10];
    const float* theta     = (const float*)d_in[11];
    const float* D_skip    = (const float*)d_in[12];
    const float* mimo_U    = (const float*)d_in[13];
    const float* mimo_V    = (const float*)d_in[14];
    const float* Wout      = (const float*)d_in[15];
    const float* ln2_g     = (const float*)d_in[16];
    const float* ln2_b     = (const float*)d_in[17];
    const float* attn_in_w = (const float*)d_in[18];
    const float* attn_in_b = (const float*)d_in[19];
    const float* attn_out_w= (const float*)d_in[20];
    const float* attn_out_b= (const float*)d_in[21];
    const float* ln3_g     = (const float*)d_in[22];
    const float* ln3_b     = (const float*)d_in[23];
    const float* Wg        = (const float*)d_in[24];
    const float* Wu        = (const float*)d_in[25];
    const float* Wd        = (const float*)d_in[26];

    float* W = (float*)d_ws;
    unsigned short* wts = (unsigned short*)W;
    unsigned short* ub  = (unsigned short*)(W + OFF_UB);
    float* x32          = W + OFF_X32;
    unsigned short* x2b = (unsigned short*)(W + OFF_X2B);
    unsigned short* bmb = (unsigned short*)(W + OFF_BMB);
    unsigned short* cmb = (unsigned short*)(W + OFF_CMB);
    float4* dtp         = (float4*)(W + OFF_DTP);
    unsigned short* zgb = (unsigned short*)(W + OFF_ZG);
    unsigned short* ygb = (unsigned short*)(W + OFF_YGB);
    float* yout         = W + OFF_YOUT;
    float* z1           = W + OFF_Z1;
    unsigned short* znb = (unsigned short*)(W + OFF_ZNB);
    unsigned short* qkvb= (unsigned short*)(W + OFF_QKV);
    unsigned short* ob  = (unsigned short*)(W + OFF_OB);
    float* z2           = W + OFF_Z2;
    unsigned short* zfb = (unsigned short*)(W + OFF_ZFB);
    unsigned short* sgb = (unsigned short*)(W + OFF_SGB);
    unsigned short* ggb = (unsigned short*)(W + OFF_GGB);

    // weight prep (every call; idempotent)
    prep_w<<<5888, 256, 0, stream>>>(Wx, Wb, Wc, Wz, Wout, attn_in_w, attn_out_w,
                                     Wg, Wu, Wd, mimo_U, mimo_V, wts);
    // ---------------- (a) intra-band Mamba3 ----------------
    ln1_kernel<<<4096, 256, 0, stream>>>(z, ln1_g, ln1_b, ub);
    mfma_gemm<<<dim3(2, 32), 256, 0, stream>>>(ub, wts + W_X, nullptr, nullptr, nullptr, x32, 256, 256, 0, 0);
    conv_silu_kernel<<<4096, 256, 0, stream>>>(x32, conv_w, x2b);
    dt_small<<<4096, 64, 0, stream>>>(ub, Wdt, dt_bias, A_log, theta, dtp);
    mfma_gemm<<<dim3(4, 32), 256, 0, stream>>>(ub, wts + W_B, nullptr, nullptr, nullptr, bmb, 512, 256, 0, 1);
    mfma_gemm<<<dim3(4, 32), 256, 0, stream>>>(ub, wts + W_C, nullptr, nullptr, nullptr, cmb, 512, 256, 0, 1);
    mfma_gemm<<<dim3(2, 32), 256, 0, stream>>>(ub, wts + W_Z, nullptr, nullptr, nullptr, zgb, 256, 256, 1, 1);
    scan3_kernel<<<1024, 64, 0, stream>>>(x2b, bmb, cmb, dtp, D_skip, zgb, ygb);
    mfma_gemm<<<dim3(2, 32), 256, 0, stream>>>(ygb, wts + W_O, nullptr, nullptr, nullptr, yout, 256, 256, 0, 0);
    addres_ln2_kernel<<<4096, 256, 0, stream>>>(z, yout, ln2_g, ln2_b, z1, znb);
    // ---------------- (b) inter-band windowed attention ----------------
    mfma_gemm<<<dim3(6, 32), 256, 0, stream>>>(znb, wts + W_QKV, attn_in_b, nullptr, nullptr, qkvb, 768, 256, 0, 1);
    attn_kernel<<<1024, 256, 0, stream>>>(qkvb, ob);
    mfma_gemm<<<dim3(2, 32), 256, 0, stream>>>(ob, wts + W_AO, attn_out_b, nullptr, z1, z2, 256, 256, 0, 0);
    // ---------------- (c) SwiGLU FFN ----------------
    ln_f32_kernel<<<4096, 256, 0, stream>>>(z2, ln3_g, ln3_b, zfb);
    mfma_gemm<<<dim3(8, 32), 256, 0, stream>>>(zfb, wts + W_G, nullptr, nullptr, nullptr, sgb, 1024, 256, 1, 1);
    mfma_gemm<<<dim3(8, 32), 256, 0, stream>>>(zfb, wts + W_U, nullptr, sgb, nullptr, ggb, 1024, 256, 0, 1);
    mfma_gemm<<<dim3(2, 32), 256, 0, stream>>>(ggb, wts + W_D, nullptr, nullptr, z2, (float*)d_out, 256, 1024, 0, 0);
}

// Round 5
// 308.940 us; speedup vs baseline: 1.4231x; 1.4231x over previous
//
#include <hip/hip_runtime.h>
#include <hip/hip_bf16.h>
#include <math.h>

typedef __hip_bfloat16 bf16;
typedef __attribute__((ext_vector_type(8))) short s16x8;
typedef __attribute__((ext_vector_type(4))) float f32x4;

__device__ __forceinline__ float siluf(float x) { return x / (1.f + __expf(-x)); }
__device__ __forceinline__ float bits2f(unsigned short u) {
    union { float f; unsigned i; } v; v.i = ((unsigned)u) << 16; return v.f;
}
__device__ __forceinline__ unsigned short f2bits(float f) {
    return (unsigned short)__bfloat16_as_ushort(__float2bfloat16(f));
}
__device__ __forceinline__ uint4 bmul8(uint4 g, uint4 u) {
    const unsigned short* gs = (const unsigned short*)&g;
    const unsigned short* us = (const unsigned short*)&u;
    uint4 r; unsigned short* rs = (unsigned short*)&r;
    #pragma unroll
    for (int i = 0; i < 8; i++) rs[i] = f2bits(bits2f(gs[i]) * bits2f(us[i]));
    return r;
}

// ---------------- workspace offsets (float units) ----------------
#define KFL 1024
#define OFF_UB   (768*KFL)
#define OFF_DTV  (1280*KFL)
#define OFF_MA   (1296*KFL)
#define OFF_PH   (1312*KFL)
#define OFF_BMB  (1344*KFL)
#define OFF_CMB  (2368*KFL)
#define OFF_ZGB  (3392*KFL)
#define OFF_X32  (3904*KFL)
#define OFF_X2T  (4928*KFL)
#define OFF_P    (5440*KFL)
#define OFF_YGB  (7488*KFL)
#define OFF_Z1   (8000*KFL)
#define OFF_YOUT OFF_X32
#define OFF_ZNB  OFF_UB
#define OFF_QKV  OFF_BMB
#define OFF_OB   (2880*KFL)
#define OFF_Z2   OFF_P
#define OFF_ZFB  (6464*KFL)
#define OFF_SGU  OFF_BMB

// weight element offsets (bf16 elements, from ws base)
#define W_BCZX 0
#define W_OUT  393216
#define W_QKV  458752
#define W_AO   655360
#define W_GU   720896
#define W_D    1245184

// ------- fused weight prep: fp32 -> bf16 [N,K], MIMO-mix folded into Wb ----
__global__ __launch_bounds__(256) void prep_w(
    const float* __restrict__ Wx, const float* __restrict__ Wb,
    const float* __restrict__ Wc, const float* __restrict__ Wz,
    const float* __restrict__ Wo, const float* __restrict__ Wqkv,
    const float* __restrict__ Wao, const float* __restrict__ Wg,
    const float* __restrict__ Wu, const float* __restrict__ Wd,
    const float* __restrict__ U, const float* __restrict__ V,
    unsigned short* __restrict__ out)
{
    int b = blockIdx.x;
    if (b < 1536) {
        // mega BCZX weight: rows [0,512)=Bmix [512,1024)=C [1024,1280)=Z [1280,1536)=X
        int idx = b * 256 + threadIdx.x;
        int n = idx >> 8, k = idx & 255;
        float v;
        if (n < 512) {
            int h = n >> 7, nn = n & 127;
            v = 0.f;
            #pragma unroll
            for (int g = 0; g < 4; g++) {
                float mm = 0.f;
                #pragma unroll
                for (int j = 0; j < 4; j++) mm += U[h * 4 + j] * V[g * 4 + j];
                v += mm * Wb[k * 512 + g * 128 + nn];
            }
        } else if (n < 1024) v = Wc[k * 512 + (n - 512)];
        else if (n < 1280)   v = Wz[k * 256 + (n - 1024)];
        else                 v = Wx[k * 256 + (n - 1280)];
        out[W_BCZX + idx] = f2bits(v);
        return;
    }
    const float* src; int dst, kshift, Nn, trans, segb;
    if      (b < 1792) { src=Wo;   dst=W_OUT; kshift=8;  Nn=256;  trans=1; segb=1536; }
    else if (b < 2560) { src=Wqkv; dst=W_QKV; kshift=8;  Nn=256;  trans=0; segb=1792; }
    else if (b < 2816) { src=Wao;  dst=W_AO;  kshift=8;  Nn=256;  trans=0; segb=2560; }
    else if (b < 4864) { src=nullptr; dst=W_GU; kshift=8; Nn=1024; trans=1; segb=2816; }
    else               { src=Wd;   dst=W_D;   kshift=10; Nn=256;  trans=1; segb=4864; }
    int idx = (b - segb) * 256 + threadIdx.x;
    float v;
    if (dst == W_GU) {
        int n = idx >> 8, k = idx & 255;
        v = (n < 1024) ? Wg[k * 1024 + n] : Wu[k * 1024 + (n - 1024)];
    } else if (trans) {
        int n = idx >> kshift, k = idx & ((1 << kshift) - 1);
        v = src[k * Nn + n];
    } else {
        v = src[idx];
    }
    out[dst + idx] = f2bits(v);
}

// ---------------- LN1: z (B,T,K,D) fp32 -> u bf16 band-major (BK,T,D) -------------
__global__ __launch_bounds__(256) void ln1_kernel(const float* __restrict__ z,
    const float* __restrict__ g, const float* __restrict__ b,
    unsigned short* __restrict__ u)
{
    int r = blockIdx.x;
    int t = r & 255, bk = r >> 8;
    int b_ = bk >> 3, k = bk & 7;
    int src = ((b_ * 256 + t) * 8 + k) * 256;
    int d = threadIdx.x;
    float x = z[src + d];
    __shared__ float lds[4];
    float v = x;
    #pragma unroll
    for (int off = 32; off; off >>= 1) v += __shfl_xor(v, off, 64);
    if ((threadIdx.x & 63) == 0) lds[threadIdx.x >> 6] = v;
    __syncthreads();
    float mean = (lds[0] + lds[1] + lds[2] + lds[3]) * (1.f / 256.f);
    __syncthreads();
    float c = x - mean;
    v = c * c;
    #pragma unroll
    for (int off = 32; off; off >>= 1) v += __shfl_xor(v, off, 64);
    if ((threadIdx.x & 63) == 0) lds[threadIdx.x >> 6] = v;
    __syncthreads();
    float var = (lds[0] + lds[1] + lds[2] + lds[3]) * (1.f / 256.f);
    u[r * 256 + d] = f2bits(c * rsqrtf(var + 1e-5f) * g[d] + b[d]);
}

// generic f32-in LN -> bf16 out
__global__ __launch_bounds__(256) void ln_f32_kernel(const float* __restrict__ zin,
    const float* __restrict__ g, const float* __restrict__ b,
    unsigned short* __restrict__ out)
{
    int r = blockIdx.x;
    int d = threadIdx.x;
    float x = zin[r * 256 + d];
    __shared__ float lds[4];
    float v = x;
    #pragma unroll
    for (int off = 32; off; off >>= 1) v += __shfl_xor(v, off, 64);
    if ((threadIdx.x & 63) == 0) lds[threadIdx.x >> 6] = v;
    __syncthreads();
    float mean = (lds[0] + lds[1] + lds[2] + lds[3]) * (1.f / 256.f);
    __syncthreads();
    float c = x - mean;
    v = c * c;
    #pragma unroll
    for (int off = 32; off; off >>= 1) v += __shfl_xor(v, off, 64);
    if ((threadIdx.x & 63) == 0) lds[threadIdx.x >> 6] = v;
    __syncthreads();
    float var = (lds[0] + lds[1] + lds[2] + lds[3]) * (1.f / 256.f);
    out[r * 256 + d] = f2bits(c * rsqrtf(var + 1e-5f) * g[d] + b[d]);
}

// ---- fused residual-add (band-major transpose) + LN2 ----
__global__ __launch_bounds__(256) void addres_ln2_kernel(const float* __restrict__ z,
    const float* __restrict__ yout, const float* __restrict__ g,
    const float* __restrict__ b, float* __restrict__ z1,
    unsigned short* __restrict__ znb)
{
    int rt = blockIdx.x;
    int k = rt & 7, bt = rt >> 3;
    int t = bt & 255, b_ = bt >> 8;
    int rb = (b_ * 8 + k) * 256 + t;
    int d = threadIdx.x;
    float x = z[rt * 256 + d] + yout[rb * 256 + d];
    z1[rt * 256 + d] = x;
    __shared__ float lds[4];
    float v = x;
    #pragma unroll
    for (int off = 32; off; off >>= 1) v += __shfl_xor(v, off, 64);
    if ((threadIdx.x & 63) == 0) lds[threadIdx.x >> 6] = v;
    __syncthreads();
    float mean = (lds[0] + lds[1] + lds[2] + lds[3]) * (1.f / 256.f);
    __syncthreads();
    float c = x - mean;
    v = c * c;
    #pragma unroll
    for (int off = 32; off; off >>= 1) v += __shfl_xor(v, off, 64);
    if ((threadIdx.x & 63) == 0) lds[threadIdx.x >> 6] = v;
    __syncthreads();
    float var = (lds[0] + lds[1] + lds[2] + lds[3]) * (1.f / 256.f);
    znb[rt * 256 + d] = f2bits(c * rsqrtf(var + 1e-5f) * g[d] + b[d]);
}

// ---------------- generic MFMA bf16 GEMM (128x128 tile, 4 waves) ----------------
__global__ __launch_bounds__(256) void mfma_gemm(
    const unsigned short* __restrict__ A, const unsigned short* __restrict__ Bt,
    const float* __restrict__ bias, const float* __restrict__ resid,
    void* __restrict__ C, int N, int K, int act, int out_bf16)
{
    __shared__ unsigned short As[128 * 40];
    __shared__ unsigned short Bs[128 * 40];
    int tid = threadIdx.x;
    int n0 = blockIdx.x * 128, m0 = blockIdx.y * 128;
    int w = tid >> 6, l = tid & 63;
    int mwave = (w >> 1) * 64, nwave = (w & 1) * 64;
    f32x4 acc[4][4] = {};
    int srow = tid >> 2, sc = (tid & 3) * 8;
    const unsigned short* Ap = A + (size_t)(m0 + srow) * K + sc;
    const unsigned short* Bp = Bt + (size_t)(n0 + srow) * K + sc;
    int lq = l & 15, lh = l >> 4, ko = lh * 8;
    for (int k0 = 0; k0 < K; k0 += 32) {
        uint4 a0 = *(const uint4*)(Ap + k0);
        uint4 a1 = *(const uint4*)(Ap + (size_t)64 * K + k0);
        uint4 b0 = *(const uint4*)(Bp + k0);
        uint4 b1 = *(const uint4*)(Bp + (size_t)64 * K + k0);
        if (k0) __syncthreads();
        *(uint4*)&As[srow * 40 + sc] = a0;
        *(uint4*)&As[(srow + 64) * 40 + sc] = a1;
        *(uint4*)&Bs[srow * 40 + sc] = b0;
        *(uint4*)&Bs[(srow + 64) * 40 + sc] = b1;
        __syncthreads();
        s16x8 bfr[4];
        #pragma unroll
        for (int nf = 0; nf < 4; nf++)
            bfr[nf] = *(const s16x8*)&Bs[(nwave + nf * 16 + lq) * 40 + ko];
        #pragma unroll
        for (int mf = 0; mf < 4; mf++) {
            s16x8 af = *(const s16x8*)&As[(mwave + mf * 16 + lq) * 40 + ko];
            #pragma unroll
            for (int nf = 0; nf < 4; nf++)
                acc[mf][nf] = __builtin_amdgcn_mfma_f32_16x16x32_bf16(af, bfr[nf], acc[mf][nf], 0, 0, 0);
        }
    }
    #pragma unroll
    for (int mf = 0; mf < 4; mf++) {
        #pragma unroll
        for (int nf = 0; nf < 4; nf++) {
            int n = n0 + nwave + nf * 16 + lq;
            float bs_ = bias ? bias[n] : 0.f;
            #pragma unroll
            for (int r = 0; r < 4; r++) {
                int m = m0 + mwave + mf * 16 + lh * 4 + r;
                float v = acc[mf][nf][r] + bs_;
                if (act) v = siluf(v);
                if (resid) v += resid[(size_t)m * N + n];
                if (out_bf16) ((unsigned short*)C)[(size_t)m * N + n] = f2bits(v);
                else          ((float*)C)[(size_t)m * N + n] = v;
            }
        }
    }
}

// ---------------- mega GEMM BCZX: N=1536, segmented epilogue ----------------
__global__ __launch_bounds__(256) void gemm_bczx(
    const unsigned short* __restrict__ A, const unsigned short* __restrict__ Bt,
    unsigned short* __restrict__ bmb, unsigned short* __restrict__ cmb,
    unsigned short* __restrict__ zgb, float* __restrict__ x32)
{
    __shared__ unsigned short As[128 * 40];
    __shared__ unsigned short Bs[128 * 40];
    const int K = 256;
    int tid = threadIdx.x;
    int n0 = blockIdx.x * 128, m0 = blockIdx.y * 128;
    int w = tid >> 6, l = tid & 63;
    int mwave = (w >> 1) * 64, nwave = (w & 1) * 64;
    f32x4 acc[4][4] = {};
    int srow = tid >> 2, sc = (tid & 3) * 8;
    const unsigned short* Ap = A + (size_t)(m0 + srow) * K + sc;
    const unsigned short* Bp = Bt + (size_t)(n0 + srow) * K + sc;
    int lq = l & 15, lh = l >> 4, ko = lh * 8;
    for (int k0 = 0; k0 < K; k0 += 32) {
        uint4 a0 = *(const uint4*)(Ap + k0);
        uint4 a1 = *(const uint4*)(Ap + (size_t)64 * K + k0);
        uint4 b0 = *(const uint4*)(Bp + k0);
        uint4 b1 = *(const uint4*)(Bp + (size_t)64 * K + k0);
        if (k0) __syncthreads();
        *(uint4*)&As[srow * 40 + sc] = a0;
        *(uint4*)&As[(srow + 64) * 40 + sc] = a1;
        *(uint4*)&Bs[srow * 40 + sc] = b0;
        *(uint4*)&Bs[(srow + 64) * 40 + sc] = b1;
        __syncthreads();
        s16x8 bfr[4];
        #pragma unroll
        for (int nf = 0; nf < 4; nf++)
            bfr[nf] = *(const s16x8*)&Bs[(nwave + nf * 16 + lq) * 40 + ko];
        #pragma unroll
        for (int mf = 0; mf < 4; mf++) {
            s16x8 af = *(const s16x8*)&As[(mwave + mf * 16 + lq) * 40 + ko];
            #pragma unroll
            for (int nf = 0; nf < 4; nf++)
                acc[mf][nf] = __builtin_amdgcn_mfma_f32_16x16x32_bf16(af, bfr[nf], acc[mf][nf], 0, 0, 0);
        }
    }
    #pragma unroll
    for (int mf = 0; mf < 4; mf++) {
        #pragma unroll
        for (int nf = 0; nf < 4; nf++) {
            int n = n0 + nwave + nf * 16 + lq;
            #pragma unroll
            for (int r = 0; r < 4; r++) {
                int m = m0 + mwave + mf * 16 + lh * 4 + r;
                float v = acc[mf][nf][r];
                if (n < 512)       bmb[(size_t)m * 512 + n] = f2bits(v);
                else if (n < 1024) cmb[(size_t)m * 512 + (n - 512)] = f2bits(v);
                else if (n < 1280) zgb[(size_t)m * 256 + (n - 1024)] = f2bits(siluf(v));
                else               x32[(size_t)m * 256 + (n - 1280)] = v;
            }
        }
    }
}

// ---------------- mega GEMM GU: N=2048, silu on first half ----------------
__global__ __launch_bounds__(256) void gemm_gu(
    const unsigned short* __restrict__ A, const unsigned short* __restrict__ Bt,
    unsigned short* __restrict__ sgu)
{
    __shared__ unsigned short As[128 * 40];
    __shared__ unsigned short Bs[128 * 40];
    const int K = 256;
    int tid = threadIdx.x;
    int n0 = blockIdx.x * 128, m0 = blockIdx.y * 128;
    int w = tid >> 6, l = tid & 63;
    int mwave = (w >> 1) * 64, nwave = (w & 1) * 64;
    f32x4 acc[4][4] = {};
    int srow = tid >> 2, sc = (tid & 3) * 8;
    const unsigned short* Ap = A + (size_t)(m0 + srow) * K + sc;
    const unsigned short* Bp = Bt + (size_t)(n0 + srow) * K + sc;
    int lq = l & 15, lh = l >> 4, ko = lh * 8;
    for (int k0 = 0; k0 < K; k0 += 32) {
        uint4 a0 = *(const uint4*)(Ap + k0);
        uint4 a1 = *(const uint4*)(Ap + (size_t)64 * K + k0);
        uint4 b0 = *(const uint4*)(Bp + k0);
        uint4 b1 = *(const uint4*)(Bp + (size_t)64 * K + k0);
        if (k0) __syncthreads();
        *(uint4*)&As[srow * 40 + sc] = a0;
        *(uint4*)&As[(srow + 64) * 40 + sc] = a1;
        *(uint4*)&Bs[srow * 40 + sc] = b0;
        *(uint4*)&Bs[(srow + 64) * 40 + sc] = b1;
        __syncthreads();
        s16x8 bfr[4];
        #pragma unroll
        for (int nf = 0; nf < 4; nf++)
            bfr[nf] = *(const s16x8*)&Bs[(nwave + nf * 16 + lq) * 40 + ko];
        #pragma unroll
        for (int mf = 0; mf < 4; mf++) {
            s16x8 af = *(const s16x8*)&As[(mwave + mf * 16 + lq) * 40 + ko];
            #pragma unroll
            for (int nf = 0; nf < 4; nf++)
                acc[mf][nf] = __builtin_amdgcn_mfma_f32_16x16x32_bf16(af, bfr[nf], acc[mf][nf], 0, 0, 0);
        }
    }
    #pragma unroll
    for (int mf = 0; mf < 4; mf++) {
        #pragma unroll
        for (int nf = 0; nf < 4; nf++) {
            int n = n0 + nwave + nf * 16 + lq;
            #pragma unroll
            for (int r = 0; r < 4; r++) {
                int m = m0 + mwave + mf * 16 + lh * 4 + r;
                float v = acc[mf][nf][r];
                if (n < 1024) v = siluf(v);
                sgu[(size_t)m * 2048 + n] = f2bits(v);
            }
        }
    }
}

// ------- gemm_d2: out = (silu(G) * U) @ Wd^T + resid; A-product in staging -------
__global__ __launch_bounds__(256) void gemm_d2(
    const unsigned short* __restrict__ sgu, const unsigned short* __restrict__ Bt,
    const float* __restrict__ resid, float* __restrict__ out)
{
    __shared__ unsigned short As[128 * 40];
    __shared__ unsigned short Bs[128 * 40];
    const int K = 1024, N = 256;
    int tid = threadIdx.x;
    int n0 = blockIdx.x * 128, m0 = blockIdx.y * 128;
    int w = tid >> 6, l = tid & 63;
    int mwave = (w >> 1) * 64, nwave = (w & 1) * 64;
    f32x4 acc[4][4] = {};
    int srow = tid >> 2, sc = (tid & 3) * 8;
    const unsigned short* Ag = sgu + (size_t)(m0 + srow) * 2048 + sc;
    const unsigned short* Bp = Bt + (size_t)(n0 + srow) * K + sc;
    int lq = l & 15, lh = l >> 4, ko = lh * 8;
    for (int k0 = 0; k0 < K; k0 += 32) {
        uint4 a0 = bmul8(*(const uint4*)(Ag + k0), *(const uint4*)(Ag + 1024 + k0));
        uint4 a1 = bmul8(*(const uint4*)(Ag + (size_t)64 * 2048 + k0),
                         *(const uint4*)(Ag + (size_t)64 * 2048 + 1024 + k0));
        uint4 b0 = *(const uint4*)(Bp + k0);
        uint4 b1 = *(const uint4*)(Bp + (size_t)64 * K + k0);
        if (k0) __syncthreads();
        *(uint4*)&As[srow * 40 + sc] = a0;
        *(uint4*)&As[(srow + 64) * 40 + sc] = a1;
        *(uint4*)&Bs[srow * 40 + sc] = b0;
        *(uint4*)&Bs[(srow + 64) * 40 + sc] = b1;
        __syncthreads();
        s16x8 bfr[4];
        #pragma unroll
        for (int nf = 0; nf < 4; nf++)
            bfr[nf] = *(const s16x8*)&Bs[(nwave + nf * 16 + lq) * 40 + ko];
        #pragma unroll
        for (int mf = 0; mf < 4; mf++) {
            s16x8 af = *(const s16x8*)&As[(mwave + mf * 16 + lq) * 40 + ko];
            #pragma unroll
            for (int nf = 0; nf < 4; nf++)
                acc[mf][nf] = __builtin_amdgcn_mfma_f32_16x16x32_bf16(af, bfr[nf], acc[mf][nf], 0, 0, 0);
        }
    }
    #pragma unroll
    for (int mf = 0; mf < 4; mf++) {
        #pragma unroll
        for (int nf = 0; nf < 4; nf++) {
            int n = n0 + nwave + nf * 16 + lq;
            #pragma unroll
            for (int r = 0; r < 4; r++) {
                int m = m0 + mwave + mf * 16 + lh * 4 + r;
                out[(size_t)m * N + n] = acc[mf][nf][r] + resid[(size_t)m * N + n];
            }
        }
    }
}

// ------- dt_raw = u @ Wdt (N=4) + softplus, one wave per row -------
__global__ __launch_bounds__(64) void dt_small(const unsigned short* __restrict__ ub,
    const float* __restrict__ Wdt, const float* __restrict__ dt_bias,
    float4* __restrict__ dtv4)
{
    int r = blockIdx.x, l = threadIdx.x;
    ushort4 uv = *(const ushort4*)(ub + r * 256 + l * 4);
    float u0 = bits2f(uv.x), u1 = bits2f(uv.y), u2 = bits2f(uv.z), u3 = bits2f(uv.w);
    float4 w0 = *(const float4*)(Wdt + (l * 4 + 0) * 4);
    float4 w1 = *(const float4*)(Wdt + (l * 4 + 1) * 4);
    float4 w2 = *(const float4*)(Wdt + (l * 4 + 2) * 4);
    float4 w3 = *(const float4*)(Wdt + (l * 4 + 3) * 4);
    float p0 = u0 * w0.x + u1 * w1.x + u2 * w2.x + u3 * w3.x;
    float p1 = u0 * w0.y + u1 * w1.y + u2 * w2.y + u3 * w3.y;
    float p2 = u0 * w0.z + u1 * w1.z + u2 * w2.z + u3 * w3.z;
    float p3 = u0 * w0.w + u1 * w1.w + u2 * w2.w + u3 * w3.w;
    #pragma unroll
    for (int off = 32; off; off >>= 1) {
        p0 += __shfl_xor(p0, off, 64);
        p1 += __shfl_xor(p1, off, 64);
        p2 += __shfl_xor(p2, off, 64);
        p3 += __shfl_xor(p3, off, 64);
    }
    if (l == 0) {
        float pv[4] = {p0, p1, p2, p3}, d[4];
        #pragma unroll
        for (int h = 0; h < 4; h++) {
            float xx = pv[h] + dt_bias[h];
            d[h] = (xx > 20.f) ? xx : log1pf(__expf(xx));
        }
        dtv4[r] = make_float4(d[0], d[1], d[2], d[3]);
    }
}

// ------- cumulative sums of dt*A (log-mag) and dt*theta (phase), per bk -------
__global__ __launch_bounds__(256) void cumsum_kernel(const float4* __restrict__ dtv4,
    const float* __restrict__ A_log, const float* __restrict__ theta,
    float4* __restrict__ mA4, float4* __restrict__ ph4)
{
    int bk = blockIdx.x, t = threadIdx.x;
    int r = bk * 256 + t;
    float4 d = dtv4[r];
    float A0 = -__expf(A_log[0]), A1 = -__expf(A_log[1]);
    float A2 = -__expf(A_log[2]), A3 = -__expf(A_log[3]);
    float4 a = make_float4(d.x * A0, d.y * A1, d.z * A2, d.w * A3);
    float4 p = make_float4(d.x * theta[0], d.y * theta[1], d.z * theta[2], d.w * theta[3]);
    __shared__ float4 s1[256], s2[256];
    s1[t] = a; s2[t] = p;
    __syncthreads();
    for (int off = 1; off < 256; off <<= 1) {
        float4 u1, u2;
        int use = (t >= off);
        if (use) { u1 = s1[t - off]; u2 = s2[t - off]; }
        __syncthreads();
        if (use) {
            float4 v1 = s1[t], v2 = s2[t];
            v1.x += u1.x; v1.y += u1.y; v1.z += u1.z; v1.w += u1.w;
            v2.x += u2.x; v2.y += u2.y; v2.z += u2.z; v2.w += u2.w;
            s1[t] = v1; s2[t] = v2;
        }
        __syncthreads();
    }
    mA4[r] = s1[t]; ph4[r] = s2[t];
}

// ------- causal conv (k=4) + silu + transpose: x32 [r][d] -> x2t [bh*64+p][t] -------
__global__ __launch_bounds__(256) void conv_t_kernel(const float* __restrict__ x32,
    const float* __restrict__ w, unsigned short* __restrict__ x2t)
{
    int bhid = blockIdx.x;               // bk*4 + h
    int bk = bhid >> 2, h = bhid & 3;
    int tid = threadIdx.x;
    __shared__ float tile[256 * 65];
    #pragma unroll 8
    for (int pass = 0; pass < 64; pass++) {
        int idx = pass * 256 + tid;
        int t = idx >> 6, dd = idx & 63;
        tile[t * 65 + dd] = x32[(size_t)(bk * 256 + t) * 256 + h * 64 + dd];
    }
    __syncthreads();
    int t = tid;
    for (int p = 0; p < 64; p++) {
        float4 wv = *(const float4*)(w + (h * 64 + p) * 4);
        float acc = tile[t * 65 + p] * wv.w;
        if (t >= 1) acc += tile[(t - 1) * 65 + p] * wv.z;
        if (t >= 2) acc += tile[(t - 2) * 65 + p] * wv.y;
        if (t >= 3) acc += tile[(t - 3) * 65 + p] * wv.x;
        x2t[(size_t)(bhid * 64 + p) * 256 + t] = f2bits(siluf(acc));
    }
}

// ------- batched S = C @ B^T with decay-mask epilogue -> P bf16 -------
// grid (bx=s-tile 2, by=t-tile 2, bh 64)
__global__ __launch_bounds__(256) void gemm_s(
    const unsigned short* __restrict__ cmb, const unsigned short* __restrict__ bmb,
    const float* __restrict__ mA, const float* __restrict__ phA,
    const float* __restrict__ dtS, unsigned short* __restrict__ P)
{
    int bx = blockIdx.x, by = blockIdx.y, bh = blockIdx.z;
    int bk = bh >> 2, h = bh & 3;
    int tid = threadIdx.x;
    int w = tid >> 6, l = tid & 63;
    int mwave = (w >> 1) * 64, nwave = (w & 1) * 64;
    int lq = l & 15, lh = l >> 4, ko = lh * 8;
    unsigned short* Pout = P + (size_t)bh * 65536;
    if (by < bx) {
        #pragma unroll
        for (int mf = 0; mf < 4; mf++)
            #pragma unroll
            for (int nf = 0; nf < 4; nf++)
                #pragma unroll
                for (int r = 0; r < 4; r++) {
                    int t = by * 128 + mwave + mf * 16 + lh * 4 + r;
                    int s = bx * 128 + nwave + nf * 16 + lq;
                    Pout[t * 256 + s] = 0;
                }
        return;
    }
    __shared__ unsigned short As[128 * 40];
    __shared__ unsigned short Bs[128 * 40];
    f32x4 acc[4][4] = {};
    int srow = tid >> 2, sc = (tid & 3) * 8;
    const unsigned short* Ap = cmb + (size_t)(bk * 256 + by * 128 + srow) * 512 + h * 128 + sc;
    const unsigned short* Bp = bmb + (size_t)(bk * 256 + bx * 128 + srow) * 512 + h * 128 + sc;
    for (int k0 = 0; k0 < 128; k0 += 32) {
        uint4 a0 = *(const uint4*)(Ap + k0);
        uint4 a1 = *(const uint4*)(Ap + (size_t)64 * 512 + k0);
        uint4 b0 = *(const uint4*)(Bp + k0);
        uint4 b1 = *(const uint4*)(Bp + (size_t)64 * 512 + k0);
        if (k0) __syncthreads();
        *(uint4*)&As[srow * 40 + sc] = a0;
        *(uint4*)&As[(srow + 64) * 40 + sc] = a1;
        *(uint4*)&Bs[srow * 40 + sc] = b0;
        *(uint4*)&Bs[(srow + 64) * 40 + sc] = b1;
        __syncthreads();
        s16x8 bfr[4];
        #pragma unroll
        for (int nf = 0; nf < 4; nf++)
            bfr[nf] = *(const s16x8*)&Bs[(nwave + nf * 16 + lq) * 40 + ko];
        #pragma unroll
        for (int mf = 0; mf < 4; mf++) {
            s16x8 af = *(const s16x8*)&As[(mwave + mf * 16 + lq) * 40 + ko];
            #pragma unroll
            for (int nf = 0; nf < 4; nf++)
                acc[mf][nf] = __builtin_amdgcn_mfma_f32_16x16x32_bf16(af, bfr[nf], acc[mf][nf], 0, 0, 0);
        }
    }
    int rb4 = bk * 1024;                  // (bk*256)*4
    #pragma unroll
    for (int mf = 0; mf < 4; mf++) {
        float tmv[4], tpv[4]; int tg[4];
        #pragma unroll
        for (int r = 0; r < 4; r++) {
            tg[r] = by * 128 + mwave + mf * 16 + lh * 4 + r;
            tmv[r] = mA[rb4 + tg[r] * 4 + h];
            tpv[r] = phA[rb4 + tg[r] * 4 + h];
        }
        #pragma unroll
        for (int nf = 0; nf < 4; nf++) {
            int s = bx * 128 + nwave + nf * 16 + lq;
            float ms = mA[rb4 + s * 4 + h];
            float ps = phA[rb4 + s * 4 + h];
            float ds = dtS[rb4 + s * 4 + h];
            #pragma unroll
            for (int r = 0; r < 4; r++) {
                float wgt = (s <= tg[r])
                    ? __expf(tmv[r] - ms) * __cosf(tpv[r] - ps) * ds : 0.f;
                Pout[tg[r] * 256 + s] = f2bits(acc[mf][nf][r] * wgt);
            }
        }
    }
}

// ------- batched Y = P @ X^T with skip+gate epilogue -> ygb -------
// grid (by=t-tile 2, bh 64); tile 128(t) x 64(p), K=256(s)
__global__ __launch_bounds__(256) void gemm_y(
    const unsigned short* __restrict__ P, const unsigned short* __restrict__ x2t,
    const unsigned short* __restrict__ zgb, const float* __restrict__ Dsk,
    unsigned short* __restrict__ ygb)
{
    int by = blockIdx.x, bh = blockIdx.y;
    int bk = bh >> 2, h = bh & 3;
    int tid = threadIdx.x;
    int w = tid >> 6, l = tid & 63;
    int mwave = w * 32;
    int lq = l & 15, lh = l >> 4, ko = lh * 8;
    __shared__ unsigned short As[128 * 40];
    __shared__ unsigned short Bs[64 * 40];
    f32x4 acc[2][4] = {};
    int srow = tid >> 2, sc = (tid & 3) * 8;
    const unsigned short* Ap = P + (size_t)bh * 65536 + (size_t)(by * 128 + srow) * 256 + sc;
    const unsigned short* Bp = x2t + (size_t)bh * 16384 + (size_t)srow * 256 + sc;
    for (int k0 = 0; k0 < 256; k0 += 32) {
        uint4 a0 = *(const uint4*)(Ap + k0);
        uint4 a1 = *(const uint4*)(Ap + 64 * 256 + k0);
        uint4 b0 = *(const uint4*)(Bp + k0);
        if (k0) __syncthreads();
        *(uint4*)&As[srow * 40 + sc] = a0;
        *(uint4*)&As[(srow + 64) * 40 + sc] = a1;
        *(uint4*)&Bs[srow * 40 + sc] = b0;
        __syncthreads();
        s16x8 bfr[4];
        #pragma unroll
        for (int nf = 0; nf < 4; nf++)
            bfr[nf] = *(const s16x8*)&Bs[(nf * 16 + lq) * 40 + ko];
        #pragma unroll
        for (int mf = 0; mf < 2; mf++) {
            s16x8 af = *(const s16x8*)&As[(mwave + mf * 16 + lq) * 40 + ko];
            #pragma unroll
            for (int nf = 0; nf < 4; nf++)
                acc[mf][nf] = __builtin_amdgcn_mfma_f32_16x16x32_bf16(af, bfr[nf], acc[mf][nf], 0, 0, 0);
        }
    }
    float dsk = Dsk[h];
    #pragma unroll
    for (int mf = 0; mf < 2; mf++) {
        #pragma unroll
        for (int nf = 0; nf < 4; nf++) {
            int p = nf * 16 + lq;
            #pragma unroll
            for (int r = 0; r < 4; r++) {
                int t = by * 128 + mwave + mf * 16 + lh * 4 + r;
                float xv = bits2f(x2t[(size_t)bh * 16384 + p * 256 + t]);
                float zg = bits2f(zgb[(size_t)(bk * 256 + t) * 256 + h * 64 + p]);
                ygb[(size_t)(bk * 256 + t) * 256 + h * 64 + p] =
                    f2bits((acc[mf][nf][r] + dsk * xv) * zg);
            }
        }
    }
}

// ---------------- windowed attention (bf16 in/out) ----------------
__global__ __launch_bounds__(256) void attn_kernel(const unsigned short* __restrict__ qkv,
    unsigned short* __restrict__ o)
{
    int m = blockIdx.x >> 1, w = blockIdx.x & 1;
    int tid = threadIdx.x;
    int h = tid >> 6, d = tid & 63;
    __shared__ float qs[4][256], ks[4][256], vs[4][256];
    #pragma unroll
    for (int j = 0; j < 4; j++) {
        int row = m * 8 + w * 4 + j;
        int base = row * 768;
        qs[j][tid] = bits2f(qkv[base + tid]);
        ks[j][tid] = bits2f(qkv[base + 256 + tid]);
        vs[j][tid] = bits2f(qkv[base + 512 + tid]);
    }
    __syncthreads();
    float sc[4][4];
    #pragma unroll
    for (int qi = 0; qi < 4; qi++)
        #pragma unroll
        for (int ki = 0; ki < 4; ki++) {
            float v = qs[qi][h * 64 + d] * ks[ki][h * 64 + d];
            #pragma unroll
            for (int off = 32; off; off >>= 1) v += __shfl_xor(v, off, 64);
            sc[qi][ki] = v * 0.125f;
        }
    #pragma unroll
    for (int qi = 0; qi < 4; qi++) {
        float mx = fmaxf(fmaxf(sc[qi][0], sc[qi][1]), fmaxf(sc[qi][2], sc[qi][3]));
        float e0 = __expf(sc[qi][0] - mx), e1 = __expf(sc[qi][1] - mx);
        float e2 = __expf(sc[qi][2] - mx), e3 = __expf(sc[qi][3] - mx);
        float inv = 1.f / (e0 + e1 + e2 + e3);
        float ov = (e0 * vs[0][h * 64 + d] + e1 * vs[1][h * 64 + d] +
                    e2 * vs[2][h * 64 + d] + e3 * vs[3][h * 64 + d]) * inv;
        o[(m * 8 + w * 4 + qi) * 256 + h * 64 + d] = f2bits(ov);
    }
}

extern "C" void kernel_launch(void* const* d_in, const int* in_sizes, int n_in,
                              void* d_out, int out_size, void* d_ws, size_t ws_size,
                              hipStream_t stream)
{
    const float* z         = (const float*)d_in[0];
    const float* ln1_g     = (const float*)d_in[1];
    const float* ln1_b     = (const float*)d_in[2];
    const float* Wx        = (const float*)d_in[3];
    const float* conv_w    = (const float*)d_in[4];
    const float* Wz        = (const float*)d_in[5];
    const float* Wb        = (const float*)d_in[6];
    const float* Wc        = (const float*)d_in[7];
    const float* Wdt       = (const float*)d_in[8];
    const float* dt_bias   = (const float*)d_in[9];
    const float* A_log     = (const float*)d_in[10];
    const float* theta     = (const float*)d_in[11];
    const float* D_skip    = (const float*)d_in[12];
    const float* mimo_U    = (const float*)d_in[13];
    const float* mimo_V    = (const float*)d_in[14];
    const float* Wout      = (const float*)d_in[15];
    const float* ln2_g     = (const float*)d_in[16];
    const float* ln2_b     = (const float*)d_in[17];
    const float* attn_in_w = (const float*)d_in[18];
    const float* attn_in_b = (const float*)d_in[19];
    const float* attn_out_w= (const float*)d_in[20];
    const float* attn_out_b= (const float*)d_in[21];
    const float* ln3_g     = (const float*)d_in[22];
    const float* ln3_b     = (const float*)d_in[23];
    const float* Wg        = (const float*)d_in[24];
    const float* Wu        = (const float*)d_in[25];
    const float* Wd        = (const float*)d_in[26];

    float* W = (float*)d_ws;
    unsigned short* wts = (unsigned short*)W;
    unsigned short* ub  = (unsigned short*)(W + OFF_UB);
    float4* dtv4        = (float4*)(W + OFF_DTV);
    float4* mA4         = (float4*)(W + OFF_MA);
    float4* ph4         = (float4*)(W + OFF_PH);
    unsigned short* bmb = (unsigned short*)(W + OFF_BMB);
    unsigned short* cmb = (unsigned short*)(W + OFF_CMB);
    unsigned short* zgb = (unsigned short*)(W + OFF_ZGB);
    float* x32          = W + OFF_X32;
    unsigned short* x2t = (unsigned short*)(W + OFF_X2T);
    unsigned short* pbuf= (unsigned short*)(W + OFF_P);
    unsigned short* ygb = (unsigned short*)(W + OFF_YGB);
    float* yout         = W + OFF_YOUT;
    float* z1           = W + OFF_Z1;
    unsigned short* znb = (unsigned short*)(W + OFF_ZNB);
    unsigned short* qkvb= (unsigned short*)(W + OFF_QKV);
    unsigned short* ob  = (unsigned short*)(W + OFF_OB);
    float* z2           = W + OFF_Z2;
    unsigned short* zfb = (unsigned short*)(W + OFF_ZFB);
    unsigned short* sgu = (unsigned short*)(W + OFF_SGU);

    prep_w<<<5888, 256, 0, stream>>>(Wx, Wb, Wc, Wz, Wout, attn_in_w, attn_out_w,
                                     Wg, Wu, Wd, mimo_U, mimo_V, wts);
    // ---------------- (a) intra-band Mamba3 (GEMM-ized scan) ----------------
    ln1_kernel<<<4096, 256, 0, stream>>>(z, ln1_g, ln1_b, ub);
    dt_small<<<4096, 64, 0, stream>>>(ub, Wdt, dt_bias, dtv4);
    cumsum_kernel<<<16, 256, 0, stream>>>(dtv4, A_log, theta, mA4, ph4);
    gemm_bczx<<<dim3(12, 32), 256, 0, stream>>>(ub, wts + W_BCZX, bmb, cmb, zgb, x32);
    conv_t_kernel<<<64, 256, 0, stream>>>(x32, conv_w, x2t);
    gemm_s<<<dim3(2, 2, 64), 256, 0, stream>>>(cmb, bmb, (const float*)mA4,
                                               (const float*)ph4, (const float*)dtv4, pbuf);
    gemm_y<<<dim3(2, 64), 256, 0, stream>>>(pbuf, x2t, zgb, D_skip, ygb);
    mfma_gemm<<<dim3(2, 32), 256, 0, stream>>>(ygb, wts + W_OUT, nullptr, nullptr, yout, 256, 256, 0, 0);
    addres_ln2_kernel<<<4096, 256, 0, stream>>>(z, yout, ln2_g, ln2_b, z1, znb);
    // ---------------- (b) inter-band windowed attention ----------------
    mfma_gemm<<<dim3(6, 32), 256, 0, stream>>>(znb, wts + W_QKV, attn_in_b, nullptr, qkvb, 768, 256, 0, 1);
    attn_kernel<<<1024, 256, 0, stream>>>(qkvb, ob);
    mfma_gemm<<<dim3(2, 32), 256, 0, stream>>>(ob, wts + W_AO, attn_out_b, z1, z2, 256, 256, 0, 0);
    // ---------------- (c) SwiGLU FFN ----------------
    ln_f32_kernel<<<4096, 256, 0, stream>>>(z2, ln3_g, ln3_b, zfb);
    gemm_gu<<<dim3(16, 32), 256, 0, stream>>>(zfb, wts + W_GU, sgu);
    gemm_d2<<<dim3(2, 32), 256, 0, stream>>>(sgu, wts + W_D, z2, (float*)d_out);
}

// Round 6
// 246.113 us; speedup vs baseline: 1.7863x; 1.2553x over previous
//
#include <hip/hip_runtime.h>
#include <hip/hip_bf16.h>
#include <math.h>

typedef __hip_bfloat16 bf16;
typedef __attribute__((ext_vector_type(8))) short s16x8;
typedef __attribute__((ext_vector_type(4))) float f32x4;

__device__ __forceinline__ float siluf(float x) { return x / (1.f + __expf(-x)); }
__device__ __forceinline__ float bits2f(unsigned short u) {
    union { float f; unsigned i; } v; v.i = ((unsigned)u) << 16; return v.f;
}
__device__ __forceinline__ unsigned short f2bits(float f) {
    return (unsigned short)__bfloat16_as_ushort(__float2bfloat16(f));
}
__device__ __forceinline__ uint4 bmul8(uint4 g, uint4 u) {
    const unsigned short* gs = (const unsigned short*)&g;
    const unsigned short* us = (const unsigned short*)&u;
    uint4 r; unsigned short* rs = (unsigned short*)&r;
    #pragma unroll
    for (int i = 0; i < 8; i++) rs[i] = f2bits(bits2f(gs[i]) * bits2f(us[i]));
    return r;
}

// ---------------- workspace offsets (float units) ----------------
#define KFL 1024
#define OFF_UB   (768*KFL)
#define OFF_DTV  (1280*KFL)
#define OFF_MA   (1296*KFL)
#define OFF_PH   (1312*KFL)
#define OFF_BMB  (1344*KFL)
#define OFF_CMB  (2368*KFL)
#define OFF_ZGB  (3392*KFL)
#define OFF_X32  (3904*KFL)
#define OFF_X2T  (4928*KFL)
#define OFF_P    (5440*KFL)
#define OFF_YGB  (7488*KFL)
#define OFF_Z1   (8000*KFL)
#define OFF_YOUT OFF_X32
#define OFF_ZNB  OFF_UB
#define OFF_QKV  OFF_BMB
#define OFF_OB   (2880*KFL)
#define OFF_Z2   OFF_P
#define OFF_ZFB  (6464*KFL)
#define OFF_SGU  OFF_BMB

// weight element offsets (bf16 elements, from ws base)
#define W_BCZX 0
#define W_OUT  393216
#define W_QKV  458752
#define W_AO   655360
#define W_GU   720896
#define W_D    1245184

// ------- tiled weight prep: fp32 [K,N] -> bf16 [N,K] via LDS transpose ----
// blocks 0..303: 64x64 transpose tiles; 304..367: linear bf16 casts (QKV, AO).
__global__ __launch_bounds__(256) void prep_w(
    const float* __restrict__ Wx, const float* __restrict__ Wb,
    const float* __restrict__ Wc, const float* __restrict__ Wz,
    const float* __restrict__ Wo, const float* __restrict__ Wqkv,
    const float* __restrict__ Wao, const float* __restrict__ Wg,
    const float* __restrict__ Wu, const float* __restrict__ Wd,
    const float* __restrict__ U, const float* __restrict__ V,
    unsigned short* __restrict__ out)
{
    int blk = blockIdx.x;
    int tid = threadIdx.x;
    if (blk >= 304) {
        // linear copies (already [N,K] in source layout)
        int off = blk - 304;
        const float* src; int dst, base;
        if (off < 48) { src = Wqkv; dst = W_QKV; base = off * 4096; }
        else          { src = Wao;  dst = W_AO;  base = (off - 48) * 4096; }
        #pragma unroll
        for (int i = 0; i < 16; i++) {
            int idx = base + tid + i * 256;
            out[dst + idx] = f2bits(src[idx]);
        }
        return;
    }
    __shared__ float lds[64 * 65];
    const float* src; int srcN, n0, sc0, k0, dstoff, dstK, mix = 0, t;
    if (blk < 32)       { t = blk;       src = Wb; srcN = 512;  dstoff = W_BCZX; dstK = 256;
                          n0 = (t >> 2) * 64;        sc0 = 0; k0 = (t & 3) * 64; mix = 1; }
    else if (blk < 64)  { t = blk - 32;  src = Wc; srcN = 512;  dstoff = W_BCZX; dstK = 256;
                          n0 = 512 + (t >> 2) * 64;  sc0 = (t >> 2) * 64; k0 = (t & 3) * 64; }
    else if (blk < 80)  { t = blk - 64;  src = Wz; srcN = 256;  dstoff = W_BCZX; dstK = 256;
                          n0 = 1024 + (t >> 2) * 64; sc0 = (t >> 2) * 64; k0 = (t & 3) * 64; }
    else if (blk < 96)  { t = blk - 80;  src = Wx; srcN = 256;  dstoff = W_BCZX; dstK = 256;
                          n0 = 1280 + (t >> 2) * 64; sc0 = (t >> 2) * 64; k0 = (t & 3) * 64; }
    else if (blk < 112) { t = blk - 96;  src = Wo; srcN = 256;  dstoff = W_OUT;  dstK = 256;
                          n0 = (t >> 2) * 64;        sc0 = n0; k0 = (t & 3) * 64; }
    else if (blk < 176) { t = blk - 112; src = Wg; srcN = 1024; dstoff = W_GU;   dstK = 256;
                          n0 = (t >> 2) * 64;        sc0 = n0; k0 = (t & 3) * 64; }
    else if (blk < 240) { t = blk - 176; src = Wu; srcN = 1024; dstoff = W_GU;   dstK = 256;
                          n0 = 1024 + (t >> 2) * 64; sc0 = (t >> 2) * 64; k0 = (t & 3) * 64; }
    else                { t = blk - 240; src = Wd; srcN = 256;  dstoff = W_D;    dstK = 1024;
                          n0 = (t >> 4) * 64;        sc0 = n0; k0 = (t & 15) * 64; }
    if (mix) {
        int h = n0 >> 7, scol = n0 & 127;
        float mm[4];
        #pragma unroll
        for (int g = 0; g < 4; g++) {
            float s = 0.f;
            #pragma unroll
            for (int j = 0; j < 4; j++) s += U[h * 4 + j] * V[g * 4 + j];
            mm[g] = s;
        }
        #pragma unroll
        for (int i = 0; i < 16; i++) {
            int idx = tid + i * 256;
            int kk = idx >> 6, nn = idx & 63;
            const float* row = src + (size_t)(k0 + kk) * 512 + scol + nn;
            float v = mm[0] * row[0] + mm[1] * row[128] + mm[2] * row[256] + mm[3] * row[384];
            lds[kk * 65 + nn] = v;
        }
    } else {
        #pragma unroll
        for (int i = 0; i < 16; i++) {
            int idx = tid + i * 256;
            int kk = idx >> 6, nn = idx & 63;
            lds[kk * 65 + nn] = src[(size_t)(k0 + kk) * srcN + sc0 + nn];
        }
    }
    __syncthreads();
    #pragma unroll
    for (int i = 0; i < 16; i++) {
        int idx = tid + i * 256;
        int nn = idx >> 6, kk = idx & 63;
        out[dstoff + (size_t)(n0 + nn) * dstK + k0 + kk] = f2bits(lds[kk * 65 + nn]);
    }
}

// ------- LN1 (z fp32 B,T,K,D -> u bf16 band-major) fused with dt = softplus(u@Wdt+b) --
__global__ __launch_bounds__(256) void ln1_dt_kernel(const float* __restrict__ z,
    const float* __restrict__ g, const float* __restrict__ b,
    const float* __restrict__ Wdt, const float* __restrict__ dt_bias,
    unsigned short* __restrict__ u, float4* __restrict__ dtv4)
{
    int r = blockIdx.x;
    int t = r & 255, bk = r >> 8;
    int b_ = bk >> 3, k = bk & 7;
    int src = ((b_ * 256 + t) * 8 + k) * 256;
    int d = threadIdx.x;
    float x = z[src + d];
    __shared__ float lds[4];
    __shared__ float dts[4][4];
    float v = x;
    #pragma unroll
    for (int off = 32; off; off >>= 1) v += __shfl_xor(v, off, 64);
    if ((d & 63) == 0) lds[d >> 6] = v;
    __syncthreads();
    float mean = (lds[0] + lds[1] + lds[2] + lds[3]) * (1.f / 256.f);
    __syncthreads();
    float c = x - mean;
    v = c * c;
    #pragma unroll
    for (int off = 32; off; off >>= 1) v += __shfl_xor(v, off, 64);
    if ((d & 63) == 0) lds[d >> 6] = v;
    __syncthreads();
    float var = (lds[0] + lds[1] + lds[2] + lds[3]) * (1.f / 256.f);
    float uval = c * rsqrtf(var + 1e-5f) * g[d] + b[d];
    u[r * 256 + d] = f2bits(uval);
    float4 wv = *(const float4*)(Wdt + d * 4);
    float q0 = uval * wv.x, q1 = uval * wv.y, q2 = uval * wv.z, q3 = uval * wv.w;
    #pragma unroll
    for (int off = 32; off; off >>= 1) {
        q0 += __shfl_xor(q0, off, 64);
        q1 += __shfl_xor(q1, off, 64);
        q2 += __shfl_xor(q2, off, 64);
        q3 += __shfl_xor(q3, off, 64);
    }
    if ((d & 63) == 0) {
        int w = d >> 6;
        dts[w][0] = q0; dts[w][1] = q1; dts[w][2] = q2; dts[w][3] = q3;
    }
    __syncthreads();
    if (d == 0) {
        float dv[4];
        #pragma unroll
        for (int h = 0; h < 4; h++) {
            float xx = dts[0][h] + dts[1][h] + dts[2][h] + dts[3][h] + dt_bias[h];
            dv[h] = (xx > 20.f) ? xx : log1pf(__expf(xx));
        }
        dtv4[r] = make_float4(dv[0], dv[1], dv[2], dv[3]);
    }
}

// generic f32-in LN -> bf16 out
__global__ __launch_bounds__(256) void ln_f32_kernel(const float* __restrict__ zin,
    const float* __restrict__ g, const float* __restrict__ b,
    unsigned short* __restrict__ out)
{
    int r = blockIdx.x;
    int d = threadIdx.x;
    float x = zin[r * 256 + d];
    __shared__ float lds[4];
    float v = x;
    #pragma unroll
    for (int off = 32; off; off >>= 1) v += __shfl_xor(v, off, 64);
    if ((d & 63) == 0) lds[d >> 6] = v;
    __syncthreads();
    float mean = (lds[0] + lds[1] + lds[2] + lds[3]) * (1.f / 256.f);
    __syncthreads();
    float c = x - mean;
    v = c * c;
    #pragma unroll
    for (int off = 32; off; off >>= 1) v += __shfl_xor(v, off, 64);
    if ((d & 63) == 0) lds[d >> 6] = v;
    __syncthreads();
    float var = (lds[0] + lds[1] + lds[2] + lds[3]) * (1.f / 256.f);
    out[r * 256 + d] = f2bits(c * rsqrtf(var + 1e-5f) * g[d] + b[d]);
}

// ---- fused residual-add (band-major transpose) + LN2 ----
__global__ __launch_bounds__(256) void addres_ln2_kernel(const float* __restrict__ z,
    const float* __restrict__ yout, const float* __restrict__ g,
    const float* __restrict__ b, float* __restrict__ z1,
    unsigned short* __restrict__ znb)
{
    int rt = blockIdx.x;
    int k = rt & 7, bt = rt >> 3;
    int t = bt & 255, b_ = bt >> 8;
    int rb = (b_ * 8 + k) * 256 + t;
    int d = threadIdx.x;
    float x = z[rt * 256 + d] + yout[rb * 256 + d];
    z1[rt * 256 + d] = x;
    __shared__ float lds[4];
    float v = x;
    #pragma unroll
    for (int off = 32; off; off >>= 1) v += __shfl_xor(v, off, 64);
    if ((d & 63) == 0) lds[d >> 6] = v;
    __syncthreads();
    float mean = (lds[0] + lds[1] + lds[2] + lds[3]) * (1.f / 256.f);
    __syncthreads();
    float c = x - mean;
    v = c * c;
    #pragma unroll
    for (int off = 32; off; off >>= 1) v += __shfl_xor(v, off, 64);
    if ((d & 63) == 0) lds[d >> 6] = v;
    __syncthreads();
    float var = (lds[0] + lds[1] + lds[2] + lds[3]) * (1.f / 256.f);
    znb[rt * 256 + d] = f2bits(c * rsqrtf(var + 1e-5f) * g[d] + b[d]);
}

// ---------------- generic MFMA bf16 GEMM (128x128 tile, 4 waves) ----------------
__global__ __launch_bounds__(256) void mfma_gemm(
    const unsigned short* __restrict__ A, const unsigned short* __restrict__ Bt,
    const float* __restrict__ bias, const float* __restrict__ resid,
    void* __restrict__ C, int N, int K, int act, int out_bf16)
{
    __shared__ unsigned short As[128 * 40];
    __shared__ unsigned short Bs[128 * 40];
    int tid = threadIdx.x;
    int n0 = blockIdx.x * 128, m0 = blockIdx.y * 128;
    int w = tid >> 6, l = tid & 63;
    int mwave = (w >> 1) * 64, nwave = (w & 1) * 64;
    f32x4 acc[4][4] = {};
    int srow = tid >> 2, sc = (tid & 3) * 8;
    const unsigned short* Ap = A + (size_t)(m0 + srow) * K + sc;
    const unsigned short* Bp = Bt + (size_t)(n0 + srow) * K + sc;
    int lq = l & 15, lh = l >> 4, ko = lh * 8;
    for (int k0 = 0; k0 < K; k0 += 32) {
        uint4 a0 = *(const uint4*)(Ap + k0);
        uint4 a1 = *(const uint4*)(Ap + (size_t)64 * K + k0);
        uint4 b0 = *(const uint4*)(Bp + k0);
        uint4 b1 = *(const uint4*)(Bp + (size_t)64 * K + k0);
        if (k0) __syncthreads();
        *(uint4*)&As[srow * 40 + sc] = a0;
        *(uint4*)&As[(srow + 64) * 40 + sc] = a1;
        *(uint4*)&Bs[srow * 40 + sc] = b0;
        *(uint4*)&Bs[(srow + 64) * 40 + sc] = b1;
        __syncthreads();
        s16x8 bfr[4];
        #pragma unroll
        for (int nf = 0; nf < 4; nf++)
            bfr[nf] = *(const s16x8*)&Bs[(nwave + nf * 16 + lq) * 40 + ko];
        #pragma unroll
        for (int mf = 0; mf < 4; mf++) {
            s16x8 af = *(const s16x8*)&As[(mwave + mf * 16 + lq) * 40 + ko];
            #pragma unroll
            for (int nf = 0; nf < 4; nf++)
                acc[mf][nf] = __builtin_amdgcn_mfma_f32_16x16x32_bf16(af, bfr[nf], acc[mf][nf], 0, 0, 0);
        }
    }
    #pragma unroll
    for (int mf = 0; mf < 4; mf++) {
        #pragma unroll
        for (int nf = 0; nf < 4; nf++) {
            int n = n0 + nwave + nf * 16 + lq;
            float bs_ = bias ? bias[n] : 0.f;
            #pragma unroll
            for (int r = 0; r < 4; r++) {
                int m = m0 + mwave + mf * 16 + lh * 4 + r;
                float v = acc[mf][nf][r] + bs_;
                if (act) v = siluf(v);
                if (resid) v += resid[(size_t)m * N + n];
                if (out_bf16) ((unsigned short*)C)[(size_t)m * N + n] = f2bits(v);
                else          ((float*)C)[(size_t)m * N + n] = v;
            }
        }
    }
}

// ---------------- 64x64-tile MFMA GEMM (4 waves, 2x2 frags each) ----------------
__global__ __launch_bounds__(256) void mfma_gemm64(
    const unsigned short* __restrict__ A, const unsigned short* __restrict__ Bt,
    const float* __restrict__ bias, const float* __restrict__ resid,
    void* __restrict__ C, int N, int K, int act, int out_bf16)
{
    __shared__ unsigned short As[64 * 40];
    __shared__ unsigned short Bs[64 * 40];
    int tid = threadIdx.x;
    int n0 = blockIdx.x * 64, m0 = blockIdx.y * 64;
    int w = tid >> 6, l = tid & 63;
    int mw = (w >> 1) * 32, nw = (w & 1) * 32;
    f32x4 acc[2][2] = {};
    int srow = tid >> 2, sc = (tid & 3) * 8;
    const unsigned short* Ap = A + (size_t)(m0 + srow) * K + sc;
    const unsigned short* Bp = Bt + (size_t)(n0 + srow) * K + sc;
    int lq = l & 15, lh = l >> 4, ko = lh * 8;
    for (int k0 = 0; k0 < K; k0 += 32) {
        uint4 a0 = *(const uint4*)(Ap + k0);
        uint4 b0 = *(const uint4*)(Bp + k0);
        if (k0) __syncthreads();
        *(uint4*)&As[srow * 40 + sc] = a0;
        *(uint4*)&Bs[srow * 40 + sc] = b0;
        __syncthreads();
        s16x8 bfr[2];
        #pragma unroll
        for (int nf = 0; nf < 2; nf++)
            bfr[nf] = *(const s16x8*)&Bs[(nw + nf * 16 + lq) * 40 + ko];
        #pragma unroll
        for (int mf = 0; mf < 2; mf++) {
            s16x8 af = *(const s16x8*)&As[(mw + mf * 16 + lq) * 40 + ko];
            #pragma unroll
            for (int nf = 0; nf < 2; nf++)
                acc[mf][nf] = __builtin_amdgcn_mfma_f32_16x16x32_bf16(af, bfr[nf], acc[mf][nf], 0, 0, 0);
        }
    }
    #pragma unroll
    for (int mf = 0; mf < 2; mf++) {
        #pragma unroll
        for (int nf = 0; nf < 2; nf++) {
            int n = n0 + nw + nf * 16 + lq;
            float bs_ = bias ? bias[n] : 0.f;
            #pragma unroll
            for (int r = 0; r < 4; r++) {
                int m = m0 + mw + mf * 16 + lh * 4 + r;
                float v = acc[mf][nf][r] + bs_;
                if (act) v = siluf(v);
                if (resid) v += resid[(size_t)m * N + n];
                if (out_bf16) ((unsigned short*)C)[(size_t)m * N + n] = f2bits(v);
                else          ((float*)C)[(size_t)m * N + n] = v;
            }
        }
    }
}

// ---------------- mega GEMM BCZX: N=1536, segmented epilogue ----------------
__global__ __launch_bounds__(256) void gemm_bczx(
    const unsigned short* __restrict__ A, const unsigned short* __restrict__ Bt,
    unsigned short* __restrict__ bmb, unsigned short* __restrict__ cmb,
    unsigned short* __restrict__ zgb, float* __restrict__ x32)
{
    __shared__ unsigned short As[128 * 40];
    __shared__ unsigned short Bs[128 * 40];
    const int K = 256;
    int tid = threadIdx.x;
    int n0 = blockIdx.x * 128, m0 = blockIdx.y * 128;
    int w = tid >> 6, l = tid & 63;
    int mwave = (w >> 1) * 64, nwave = (w & 1) * 64;
    f32x4 acc[4][4] = {};
    int srow = tid >> 2, sc = (tid & 3) * 8;
    const unsigned short* Ap = A + (size_t)(m0 + srow) * K + sc;
    const unsigned short* Bp = Bt + (size_t)(n0 + srow) * K + sc;
    int lq = l & 15, lh = l >> 4, ko = lh * 8;
    for (int k0 = 0; k0 < K; k0 += 32) {
        uint4 a0 = *(const uint4*)(Ap + k0);
        uint4 a1 = *(const uint4*)(Ap + (size_t)64 * K + k0);
        uint4 b0 = *(const uint4*)(Bp + k0);
        uint4 b1 = *(const uint4*)(Bp + (size_t)64 * K + k0);
        if (k0) __syncthreads();
        *(uint4*)&As[srow * 40 + sc] = a0;
        *(uint4*)&As[(srow + 64) * 40 + sc] = a1;
        *(uint4*)&Bs[srow * 40 + sc] = b0;
        *(uint4*)&Bs[(srow + 64) * 40 + sc] = b1;
        __syncthreads();
        s16x8 bfr[4];
        #pragma unroll
        for (int nf = 0; nf < 4; nf++)
            bfr[nf] = *(const s16x8*)&Bs[(nwave + nf * 16 + lq) * 40 + ko];
        #pragma unroll
        for (int mf = 0; mf < 4; mf++) {
            s16x8 af = *(const s16x8*)&As[(mwave + mf * 16 + lq) * 40 + ko];
            #pragma unroll
            for (int nf = 0; nf < 4; nf++)
                acc[mf][nf] = __builtin_amdgcn_mfma_f32_16x16x32_bf16(af, bfr[nf], acc[mf][nf], 0, 0, 0);
        }
    }
    #pragma unroll
    for (int mf = 0; mf < 4; mf++) {
        #pragma unroll
        for (int nf = 0; nf < 4; nf++) {
            int n = n0 + nwave + nf * 16 + lq;
            #pragma unroll
            for (int r = 0; r < 4; r++) {
                int m = m0 + mwave + mf * 16 + lh * 4 + r;
                float v = acc[mf][nf][r];
                if (n < 512)       bmb[(size_t)m * 512 + n] = f2bits(v);
                else if (n < 1024) cmb[(size_t)m * 512 + (n - 512)] = f2bits(v);
                else if (n < 1280) zgb[(size_t)m * 256 + (n - 1024)] = f2bits(siluf(v));
                else               x32[(size_t)m * 256 + (n - 1280)] = v;
            }
        }
    }
}

// ---------------- mega GEMM GU: N=2048, silu on first half ----------------
__global__ __launch_bounds__(256) void gemm_gu(
    const unsigned short* __restrict__ A, const unsigned short* __restrict__ Bt,
    unsigned short* __restrict__ sgu)
{
    __shared__ unsigned short As[128 * 40];
    __shared__ unsigned short Bs[128 * 40];
    const int K = 256;
    int tid = threadIdx.x;
    int n0 = blockIdx.x * 128, m0 = blockIdx.y * 128;
    int w = tid >> 6, l = tid & 63;
    int mwave = (w >> 1) * 64, nwave = (w & 1) * 64;
    f32x4 acc[4][4] = {};
    int srow = tid >> 2, sc = (tid & 3) * 8;
    const unsigned short* Ap = A + (size_t)(m0 + srow) * K + sc;
    const unsigned short* Bp = Bt + (size_t)(n0 + srow) * K + sc;
    int lq = l & 15, lh = l >> 4, ko = lh * 8;
    for (int k0 = 0; k0 < K; k0 += 32) {
        uint4 a0 = *(const uint4*)(Ap + k0);
        uint4 a1 = *(const uint4*)(Ap + (size_t)64 * K + k0);
        uint4 b0 = *(const uint4*)(Bp + k0);
        uint4 b1 = *(const uint4*)(Bp + (size_t)64 * K + k0);
        if (k0) __syncthreads();
        *(uint4*)&As[srow * 40 + sc] = a0;
        *(uint4*)&As[(srow + 64) * 40 + sc] = a1;
        *(uint4*)&Bs[srow * 40 + sc] = b0;
        *(uint4*)&Bs[(srow + 64) * 40 + sc] = b1;
        __syncthreads();
        s16x8 bfr[4];
        #pragma unroll
        for (int nf = 0; nf < 4; nf++)
            bfr[nf] = *(const s16x8*)&Bs[(nwave + nf * 16 + lq) * 40 + ko];
        #pragma unroll
        for (int mf = 0; mf < 4; mf++) {
            s16x8 af = *(const s16x8*)&As[(mwave + mf * 16 + lq) * 40 + ko];
            #pragma unroll
            for (int nf = 0; nf < 4; nf++)
                acc[mf][nf] = __builtin_amdgcn_mfma_f32_16x16x32_bf16(af, bfr[nf], acc[mf][nf], 0, 0, 0);
        }
    }
    #pragma unroll
    for (int mf = 0; mf < 4; mf++) {
        #pragma unroll
        for (int nf = 0; nf < 4; nf++) {
            int n = n0 + nwave + nf * 16 + lq;
            #pragma unroll
            for (int r = 0; r < 4; r++) {
                int m = m0 + mwave + mf * 16 + lh * 4 + r;
                float v = acc[mf][nf][r];
                if (n < 1024) v = siluf(v);
                sgu[(size_t)m * 2048 + n] = f2bits(v);
            }
        }
    }
}

// ------- gemm_d2 (64x64): out = (silu(G)*U) @ Wd^T + resid -------
__global__ __launch_bounds__(256) void gemm_d2(
    const unsigned short* __restrict__ sgu, const unsigned short* __restrict__ Bt,
    const float* __restrict__ resid, float* __restrict__ out)
{
    __shared__ unsigned short As[64 * 40];
    __shared__ unsigned short Bs[64 * 40];
    const int K = 1024, N = 256;
    int tid = threadIdx.x;
    int n0 = blockIdx.x * 64, m0 = blockIdx.y * 64;
    int w = tid >> 6, l = tid & 63;
    int mw = (w >> 1) * 32, nw = (w & 1) * 32;
    f32x4 acc[2][2] = {};
    int srow = tid >> 2, sc = (tid & 3) * 8;
    const unsigned short* Ag = sgu + (size_t)(m0 + srow) * 2048 + sc;
    const unsigned short* Bp = Bt + (size_t)(n0 + srow) * K + sc;
    int lq = l & 15, lh = l >> 4, ko = lh * 8;
    for (int k0 = 0; k0 < K; k0 += 32) {
        uint4 a0 = bmul8(*(const uint4*)(Ag + k0), *(const uint4*)(Ag + 1024 + k0));
        uint4 b0 = *(const uint4*)(Bp + k0);
        if (k0) __syncthreads();
        *(uint4*)&As[srow * 40 + sc] = a0;
        *(uint4*)&Bs[srow * 40 + sc] = b0;
        __syncthreads();
        s16x8 bfr[2];
        #pragma unroll
        for (int nf = 0; nf < 2; nf++)
            bfr[nf] = *(const s16x8*)&Bs[(nw + nf * 16 + lq) * 40 + ko];
        #pragma unroll
        for (int mf = 0; mf < 2; mf++) {
            s16x8 af = *(const s16x8*)&As[(mw + mf * 16 + lq) * 40 + ko];
            #pragma unroll
            for (int nf = 0; nf < 2; nf++)
                acc[mf][nf] = __builtin_amdgcn_mfma_f32_16x16x32_bf16(af, bfr[nf], acc[mf][nf], 0, 0, 0);
        }
    }
    #pragma unroll
    for (int mf = 0; mf < 2; mf++) {
        #pragma unroll
        for (int nf = 0; nf < 2; nf++) {
            int n = n0 + nw + nf * 16 + lq;
            #pragma unroll
            for (int r = 0; r < 4; r++) {
                int m = m0 + mw + mf * 16 + lh * 4 + r;
                out[(size_t)m * N + n] = acc[mf][nf][r] + resid[(size_t)m * N + n];
            }
        }
    }
}

// ------- cumulative sums of dt*A (log-mag) and dt*theta (phase), per bk -------
__global__ __launch_bounds__(256) void cumsum_kernel(const float4* __restrict__ dtv4,
    const float* __restrict__ A_log, const float* __restrict__ theta,
    float4* __restrict__ mA4, float4* __restrict__ ph4)
{
    int bk = blockIdx.x, t = threadIdx.x;
    int r = bk * 256 + t;
    float4 d = dtv4[r];
    float A0 = -__expf(A_log[0]), A1 = -__expf(A_log[1]);
    float A2 = -__expf(A_log[2]), A3 = -__expf(A_log[3]);
    float4 a = make_float4(d.x * A0, d.y * A1, d.z * A2, d.w * A3);
    float4 p = make_float4(d.x * theta[0], d.y * theta[1], d.z * theta[2], d.w * theta[3]);
    __shared__ float4 s1[256], s2[256];
    s1[t] = a; s2[t] = p;
    __syncthreads();
    for (int off = 1; off < 256; off <<= 1) {
        float4 u1, u2;
        int use = (t >= off);
        if (use) { u1 = s1[t - off]; u2 = s2[t - off]; }
        __syncthreads();
        if (use) {
            float4 v1 = s1[t], v2 = s2[t];
            v1.x += u1.x; v1.y += u1.y; v1.z += u1.z; v1.w += u1.w;
            v2.x += u2.x; v2.y += u2.y; v2.z += u2.z; v2.w += u2.w;
            s1[t] = v1; s2[t] = v2;
        }
        __syncthreads();
    }
    mA4[r] = s1[t]; ph4[r] = s2[t];
}

// ------- causal conv (k=4) + silu + transpose: x32 [r][d] -> x2t [bh*64+p][t] -------
// 256 blocks: blockIdx.x = bh*4 + tt, t-range [tt*64, tt*64+64)
__global__ __launch_bounds__(256) void conv_t_kernel(const float* __restrict__ x32,
    const float* __restrict__ w, unsigned short* __restrict__ x2t)
{
    int bhid = blockIdx.x >> 2, tt = blockIdx.x & 3;
    int bk = bhid >> 2, h = bhid & 3;
    int t0 = tt * 64;
    int tid = threadIdx.x;
    __shared__ float tile[67 * 65];
    #pragma unroll
    for (int i = 0; i < 17; i++) {
        int idx = tid + i * 256;
        if (idx < 67 * 64) {
            int tr = idx >> 6, dd = idx & 63;
            int t = t0 - 3 + tr;
            tile[tr * 65 + dd] = (t >= 0) ? x32[(size_t)(bk * 256 + t) * 256 + h * 64 + dd] : 0.f;
        }
    }
    __syncthreads();
    int wv_ = tid >> 6, lt = tid & 63;
    #pragma unroll 4
    for (int pi = 0; pi < 16; pi++) {
        int p = wv_ * 16 + pi;
        float4 wv = *(const float4*)(w + (h * 64 + p) * 4);
        float acc = tile[lt * 65 + p] * wv.x + tile[(lt + 1) * 65 + p] * wv.y +
                    tile[(lt + 2) * 65 + p] * wv.z + tile[(lt + 3) * 65 + p] * wv.w;
        x2t[(size_t)(bhid * 64 + p) * 256 + t0 + lt] = f2bits(siluf(acc));
    }
}

// ------- batched S = C @ B^T with decay-mask epilogue -> P bf16 -------
__global__ __launch_bounds__(256) void gemm_s(
    const unsigned short* __restrict__ cmb, const unsigned short* __restrict__ bmb,
    const float* __restrict__ mA, const float* __restrict__ phA,
    const float* __restrict__ dtS, unsigned short* __restrict__ P)
{
    int bx = blockIdx.x, by = blockIdx.y, bh = blockIdx.z;
    int bk = bh >> 2, h = bh & 3;
    int tid = threadIdx.x;
    int w = tid >> 6, l = tid & 63;
    int mwave = (w >> 1) * 64, nwave = (w & 1) * 64;
    int lq = l & 15, lh = l >> 4, ko = lh * 8;
    unsigned short* Pout = P + (size_t)bh * 65536;
    if (by < bx) {
        #pragma unroll
        for (int mf = 0; mf < 4; mf++)
            #pragma unroll
            for (int nf = 0; nf < 4; nf++)
                #pragma unroll
                for (int r = 0; r < 4; r++) {
                    int t = by * 128 + mwave + mf * 16 + lh * 4 + r;
                    int s = bx * 128 + nwave + nf * 16 + lq;
                    Pout[t * 256 + s] = 0;
                }
        return;
    }
    __shared__ unsigned short As[128 * 40];
    __shared__ unsigned short Bs[128 * 40];
    f32x4 acc[4][4] = {};
    int srow = tid >> 2, sc = (tid & 3) * 8;
    const unsigned short* Ap = cmb + (size_t)(bk * 256 + by * 128 + srow) * 512 + h * 128 + sc;
    const unsigned short* Bp = bmb + (size_t)(bk * 256 + bx * 128 + srow) * 512 + h * 128 + sc;
    for (int k0 = 0; k0 < 128; k0 += 32) {
        uint4 a0 = *(const uint4*)(Ap + k0);
        uint4 a1 = *(const uint4*)(Ap + (size_t)64 * 512 + k0);
        uint4 b0 = *(const uint4*)(Bp + k0);
        uint4 b1 = *(const uint4*)(Bp + (size_t)64 * 512 + k0);
        if (k0) __syncthreads();
        *(uint4*)&As[srow * 40 + sc] = a0;
        *(uint4*)&As[(srow + 64) * 40 + sc] = a1;
        *(uint4*)&Bs[srow * 40 + sc] = b0;
        *(uint4*)&Bs[(srow + 64) * 40 + sc] = b1;
        __syncthreads();
        s16x8 bfr[4];
        #pragma unroll
        for (int nf = 0; nf < 4; nf++)
            bfr[nf] = *(const s16x8*)&Bs[(nwave + nf * 16 + lq) * 40 + ko];
        #pragma unroll
        for (int mf = 0; mf < 4; mf++) {
            s16x8 af = *(const s16x8*)&As[(mwave + mf * 16 + lq) * 40 + ko];
            #pragma unroll
            for (int nf = 0; nf < 4; nf++)
                acc[mf][nf] = __builtin_amdgcn_mfma_f32_16x16x32_bf16(af, bfr[nf], acc[mf][nf], 0, 0, 0);
        }
    }
    int rb4 = bk * 1024;
    #pragma unroll
    for (int mf = 0; mf < 4; mf++) {
        float tmv[4], tpv[4]; int tg[4];
        #pragma unroll
        for (int r = 0; r < 4; r++) {
            tg[r] = by * 128 + mwave + mf * 16 + lh * 4 + r;
            tmv[r] = mA[rb4 + tg[r] * 4 + h];
            tpv[r] = phA[rb4 + tg[r] * 4 + h];
        }
        #pragma unroll
        for (int nf = 0; nf < 4; nf++) {
            int s = bx * 128 + nwave + nf * 16 + lq;
            float ms = mA[rb4 + s * 4 + h];
            float ps = phA[rb4 + s * 4 + h];
            float ds = dtS[rb4 + s * 4 + h];
            #pragma unroll
            for (int r = 0; r < 4; r++) {
                float wgt = (s <= tg[r])
                    ? __expf(tmv[r] - ms) * __cosf(tpv[r] - ps) * ds : 0.f;
                Pout[tg[r] * 256 + s] = f2bits(acc[mf][nf][r] * wgt);
            }
        }
    }
}

// ------- batched Y = P @ X^T (64x64 tiles) with skip+gate epilogue -> ygb -------
__global__ __launch_bounds__(256) void gemm_y(
    const unsigned short* __restrict__ P, const unsigned short* __restrict__ x2t,
    const unsigned short* __restrict__ zgb, const float* __restrict__ Dsk,
    unsigned short* __restrict__ ygb)
{
    int by = blockIdx.x, bh = blockIdx.y;
    int bk = bh >> 2, h = bh & 3;
    int tid = threadIdx.x;
    int w = tid >> 6, l = tid & 63;
    int mw = (w >> 1) * 32, nw = (w & 1) * 32;
    int lq = l & 15, lh = l >> 4, ko = lh * 8;
    __shared__ unsigned short As[64 * 40];
    __shared__ unsigned short Bs[64 * 40];
    f32x4 acc[2][2] = {};
    int srow = tid >> 2, sc = (tid & 3) * 8;
    const unsigned short* Ap = P + (size_t)bh * 65536 + (size_t)(by * 64 + srow) * 256 + sc;
    const unsigned short* Bp = x2t + (size_t)bh * 16384 + (size_t)srow * 256 + sc;
    for (int k0 = 0; k0 < 256; k0 += 32) {
        uint4 a0 = *(const uint4*)(Ap + k0);
        uint4 b0 = *(const uint4*)(Bp + k0);
        if (k0) __syncthreads();
        *(uint4*)&As[srow * 40 + sc] = a0;
        *(uint4*)&Bs[srow * 40 + sc] = b0;
        __syncthreads();
        s16x8 bfr[2];
        #pragma unroll
        for (int nf = 0; nf < 2; nf++)
            bfr[nf] = *(const s16x8*)&Bs[(nw + nf * 16 + lq) * 40 + ko];
        #pragma unroll
        for (int mf = 0; mf < 2; mf++) {
            s16x8 af = *(const s16x8*)&As[(mw + mf * 16 + lq) * 40 + ko];
            #pragma unroll
            for (int nf = 0; nf < 2; nf++)
                acc[mf][nf] = __builtin_amdgcn_mfma_f32_16x16x32_bf16(af, bfr[nf], acc[mf][nf], 0, 0, 0);
        }
    }
    float dsk = Dsk[h];
    #pragma unroll
    for (int mf = 0; mf < 2; mf++) {
        #pragma unroll
        for (int nf = 0; nf < 2; nf++) {
            int p = nw + nf * 16 + lq;
            #pragma unroll
            for (int r = 0; r < 4; r++) {
                int t = by * 64 + mw + mf * 16 + lh * 4 + r;
                float xv = bits2f(x2t[(size_t)bh * 16384 + p * 256 + t]);
                float zg = bits2f(zgb[(size_t)(bk * 256 + t) * 256 + h * 64 + p]);
                ygb[(size_t)(bk * 256 + t) * 256 + h * 64 + p] =
                    f2bits((acc[mf][nf][r] + dsk * xv) * zg);
            }
        }
    }
}

// ---------------- windowed attention (bf16 in/out) ----------------
__global__ __launch_bounds__(256) void attn_kernel(const unsigned short* __restrict__ qkv,
    unsigned short* __restrict__ o)
{
    int m = blockIdx.x >> 1, w = blockIdx.x & 1;
    int tid = threadIdx.x;
    int h = tid >> 6, d = tid & 63;
    __shared__ float qs[4][256], ks[4][256], vs[4][256];
    #pragma unroll
    for (int j = 0; j < 4; j++) {
        int row = m * 8 + w * 4 + j;
        int base = row * 768;
        qs[j][tid] = bits2f(qkv[base + tid]);
        ks[j][tid] = bits2f(qkv[base + 256 + tid]);
        vs[j][tid] = bits2f(qkv[base + 512 + tid]);
    }
    __syncthreads();
    float sc[4][4];
    #pragma unroll
    for (int qi = 0; qi < 4; qi++)
        #pragma unroll
        for (int ki = 0; ki < 4; ki++) {
            float v = qs[qi][h * 64 + d] * ks[ki][h * 64 + d];
            #pragma unroll
            for (int off = 32; off; off >>= 1) v += __shfl_xor(v, off, 64);
            sc[qi][ki] = v * 0.125f;
        }
    #pragma unroll
    for (int qi = 0; qi < 4; qi++) {
        float mx = fmaxf(fmaxf(sc[qi][0], sc[qi][1]), fmaxf(sc[qi][2], sc[qi][3]));
        float e0 = __expf(sc[qi][0] - mx), e1 = __expf(sc[qi][1] - mx);
        float e2 = __expf(sc[qi][2] - mx), e3 = __expf(sc[qi][3] - mx);
        float inv = 1.f / (e0 + e1 + e2 + e3);
        float ov = (e0 * vs[0][h * 64 + d] + e1 * vs[1][h * 64 + d] +
                    e2 * vs[2][h * 64 + d] + e3 * vs[3][h * 64 + d]) * inv;
        o[(m * 8 + w * 4 + qi) * 256 + h * 64 + d] = f2bits(ov);
    }
}

extern "C" void kernel_launch(void* const* d_in, const int* in_sizes, int n_in,
                              void* d_out, int out_size, void* d_ws, size_t ws_size,
                              hipStream_t stream)
{
    const float* z         = (const float*)d_in[0];
    const float* ln1_g     = (const float*)d_in[1];
    const float* ln1_b     = (const float*)d_in[2];
    const float* Wx        = (const float*)d_in[3];
    const float* conv_w    = (const float*)d_in[4];
    const float* Wz        = (const float*)d_in[5];
    const float* Wb        = (const float*)d_in[6];
    const float* Wc        = (const float*)d_in[7];
    const float* Wdt       = (const float*)d_in[8];
    const float* dt_bias   = (const float*)d_in[9];
    const float* A_log     = (const float*)d_in[10];
    const float* theta     = (const float*)d_in[11];
    const float* D_skip    = (const float*)d_in[12];
    const float* mimo_U    = (const float*)d_in[13];
    const float* mimo_V    = (const float*)d_in[14];
    const float* Wout      = (const float*)d_in[15];
    const float* ln2_g     = (const float*)d_in[16];
    const float* ln2_b     = (const float*)d_in[17];
    const float* attn_in_w = (const float*)d_in[18];
    const float* attn_in_b = (const float*)d_in[19];
    const float* attn_out_w= (const float*)d_in[20];
    const float* attn_out_b= (const float*)d_in[21];
    const float* ln3_g     = (const float*)d_in[22];
    const float* ln3_b     = (const float*)d_in[23];
    const float* Wg        = (const float*)d_in[24];
    const float* Wu        = (const float*)d_in[25];
    const float* Wd        = (const float*)d_in[26];

    float* W = (float*)d_ws;
    unsigned short* wts = (unsigned short*)W;
    unsigned short* ub  = (unsigned short*)(W + OFF_UB);
    float4* dtv4        = (float4*)(W + OFF_DTV);
    float4* mA4         = (float4*)(W + OFF_MA);
    float4* ph4         = (float4*)(W + OFF_PH);
    unsigned short* bmb = (unsigned short*)(W + OFF_BMB);
    unsigned short* cmb = (unsigned short*)(W + OFF_CMB);
    unsigned short* zgb = (unsigned short*)(W + OFF_ZGB);
    float* x32          = W + OFF_X32;
    unsigned short* x2t = (unsigned short*)(W + OFF_X2T);
    unsigned short* pbuf= (unsigned short*)(W + OFF_P);
    unsigned short* ygb = (unsigned short*)(W + OFF_YGB);
    float* yout         = W + OFF_YOUT;
    float* z1           = W + OFF_Z1;
    unsigned short* znb = (unsigned short*)(W + OFF_ZNB);
    unsigned short* qkvb= (unsigned short*)(W + OFF_QKV);
    unsigned short* ob  = (unsigned short*)(W + OFF_OB);
    float* z2           = W + OFF_Z2;
    unsigned short* zfb = (unsigned short*)(W + OFF_ZFB);
    unsigned short* sgu = (unsigned short*)(W + OFF_SGU);

    prep_w<<<368, 256, 0, stream>>>(Wx, Wb, Wc, Wz, Wout, attn_in_w, attn_out_w,
                                    Wg, Wu, Wd, mimo_U, mimo_V, wts);
    // ---------------- (a) intra-band Mamba3 (GEMM-ized scan) ----------------
    ln1_dt_kernel<<<4096, 256, 0, stream>>>(z, ln1_g, ln1_b, Wdt, dt_bias, ub, dtv4);
    cumsum_kernel<<<16, 256, 0, stream>>>(dtv4, A_log, theta, mA4, ph4);
    gemm_bczx<<<dim3(12, 32), 256, 0, stream>>>(ub, wts + W_BCZX, bmb, cmb, zgb, x32);
    conv_t_kernel<<<256, 256, 0, stream>>>(x32, conv_w, x2t);
    gemm_s<<<dim3(2, 2, 64), 256, 0, stream>>>(cmb, bmb, (const float*)mA4,
                                               (const float*)ph4, (const float*)dtv4, pbuf);
    gemm_y<<<dim3(4, 64), 256, 0, stream>>>(pbuf, x2t, zgb, D_skip, ygb);
    mfma_gemm64<<<dim3(4, 64), 256, 0, stream>>>(ygb, wts + W_OUT, nullptr, nullptr, yout, 256, 256, 0, 0);
    addres_ln2_kernel<<<4096, 256, 0, stream>>>(z, yout, ln2_g, ln2_b, z1, znb);
    // ---------------- (b) inter-band windowed attention ----------------
    mfma_gemm<<<dim3(6, 32), 256, 0, stream>>>(znb, wts + W_QKV, attn_in_b, nullptr, qkvb, 768, 256, 0, 1);
    attn_kernel<<<1024, 256, 0, stream>>>(qkvb, ob);
    mfma_gemm64<<<dim3(4, 64), 256, 0, stream>>>(ob, wts + W_AO, attn_out_b, z1, z2, 256, 256, 0, 0);
    // ---------------- (c) SwiGLU FFN ----------------
    ln_f32_kernel<<<4096, 256, 0, stream>>>(z2, ln3_g, ln3_b, zfb);
    gemm_gu<<<dim3(16, 32), 256, 0, stream>>>(zfb, wts + W_GU, sgu);
    gemm_d2<<<dim3(4, 64), 256, 0, stream>>>(sgu, wts + W_D, z2, (float*)d_out);
}